// Round 9
// baseline (609.627 us; speedup 1.0000x reference)
//
#include <hip/hip_runtime.h>
#include <hip/hip_cooperative_groups.h>
#include <math.h>

namespace cg = cooperative_groups;

typedef _Float16 half8 __attribute__((ext_vector_type(8)));
typedef float f32x4 __attribute__((ext_vector_type(4)));
typedef unsigned int u32x4 __attribute__((ext_vector_type(4)));
typedef unsigned int u32x2 __attribute__((ext_vector_type(2)));

namespace {
constexpr int kNS = 16;
constexpr int kNV = 4;
constexpr int kNG = 50;
constexpr int kHID = 64;
constexpr int kAttr = 28;                 // NS + 3*NV
constexpr int kWNUM = 400;
constexpr float kStep = 5.0f / 49.0f;
constexpr float kCoeff = -0.5f / (kStep * kStep);
constexpr float kSqrt3 = 1.7320508075688772f;
constexpr float kInvSqrt3 = 0.57735026918962576f;
constexpr float kInvSqrt20 = 0.22360679774997896f;
// Row = 208 B (13 granules): 52 words == 20 mod 32 -> 16 rows spread over 8
// bank-offset classes (2 lanes/bank = free). No XOR swizzle (r3 lesson).
constexpr int kRowB = 208;
constexpr int kAuxB = 48;                 // aux row: 20 f16 o0 (+pad)
constexpr int kImg1Bytes = 96 * 64 * 2;   // 12288
constexpr int kImg2Bytes = 64 * 400 * 2;  // 51200
}  // namespace

// f16 end-to-end (r6/r7: f16 absmax 0.06 vs threshold 0.101; bf16 too thin).
// (_Float16) cast = hardware v_cvt_f16_f32 RNE (r5: hip bf16 helpers truncate).
__device__ __forceinline__ unsigned short f2h(float x) {
  _Float16 h = (_Float16)x;
  unsigned short r;
  __builtin_memcpy(&r, &h, 2);
  return r;
}
__device__ __forceinline__ unsigned pack2(float lo, float hi) {
  return (unsigned)f2h(lo) | ((unsigned)f2h(hi) << 16);
}
__device__ __forceinline__ float h2f(unsigned short v) {
  _Float16 h;
  __builtin_memcpy(&h, &v, 2);
  return (float)h;
}

// ---------- cooperative sort pre-pass (HIGH-parallelism version) ----------
// r8 lessons: (a) do NOT fuse the MFMA body in here — register allocation
// collapses (VGPR 112->128+spills, +46MB scratch traffic, 5.6x slower).
// (b) sort phases are latency-bound: r6/r7 at 64-128 blocks = 0.2-0.7% VALU;
// r4 proved global-atomic hist/scatter <9us at 320K threads. This kernel has
// ~1KB LDS -> 8 blocks/CU -> launch 2048 blocks (524K threads).
__global__ __launch_bounds__(256) void coop_sort_kernel(
    const float* __restrict__ W1, const float* __restrict__ W2,
    unsigned short* __restrict__ img1, unsigned short* __restrict__ img2,
    const int* __restrict__ edge_index, int* __restrict__ cnt,
    int* __restrict__ cur, int2* __restrict__ sedge,
    float* __restrict__ agg, int aggN4, int N, int E) {
  cg::grid_group grid = cg::this_grid();
  const int tid = threadIdx.x;
  const int gtid = blockIdx.x * 256 + tid;
  const int gsz = gridDim.x * 256;

  // ---- phase 0: zero agg + cnt; pack W1 (padded 82->96) / W2 f16 images ----
  f32x4* agg4 = (f32x4*)agg;
  for (int i = gtid; i < aggN4; i += gsz) agg4[i] = f32x4{0.f, 0.f, 0.f, 0.f};
  for (int i = gtid; i < N; i += gsz) cnt[i] = 0;
  // img layout: element (k, n) at byte ((k>>3)*W + n)*16 + 2*(k&7)
  for (int i = gtid; i < 96 * 64 + 64 * 400; i += gsz) {
    if (i < 96 * 64) {
      const int m = i >> 6, n = i & 63;
      float v = 0.0f;
      if (m < 50) v = W1[m * 64 + n];                        // gaussian rows
      else if (m >= 56 && m < 88) v = W1[(m - 6) * 64 + n];  // ss, ds rows
      img1[((m >> 3) * 64 + n) * 8 + (m & 7)] = f2h(v);
    } else {
      const int j = i - 96 * 64;
      const int m = j / 400, n = j % 400;
      img2[((m >> 3) * 400 + n) * 8 + (m & 7)] = f2h(W2[m * 400 + n]);
    }
  }
  grid.sync();

  // ---- phase 1: histogram of dst (global atomics, 524K threads) ----
  for (int e = gtid; e < E; e += gsz) atomicAdd(&cnt[edge_index[E + e]], 1);
  grid.sync();

  // ---- phase 2: exclusive scan -> cur (block 0) ----
  if (blockIdx.x == 0) {
    __shared__ int sums[256];
    const int chunk = (N + 255) / 256;
    const int base = tid * chunk;
    int s = 0;
    for (int j = 0; j < chunk; j++) {
      const int i = base + j;
      if (i < N) s += cnt[i];
    }
    sums[tid] = s;
    __syncthreads();
    for (int d = 1; d < 256; d <<= 1) {
      const int y = (tid >= d) ? sums[tid - d] : 0;
      __syncthreads();
      sums[tid] += y;
      __syncthreads();
    }
    int run = sums[tid] - s;
    for (int j = 0; j < chunk; j++) {
      const int i = base + j;
      if (i < N) { cur[i] = run; run += cnt[i]; }
    }
  }
  grid.sync();

  // ---- phase 3: scatter into dst-sorted order (fused int2 records) ----
  for (int e = gtid; e < E; e += gsz) {
    const int s = edge_index[e];
    const int d = edge_index[E + e];
    const int p = atomicAdd(&cur[d], 1);
    sedge[p] = int2{s, d};
  }
}

// ---------- main MFMA edge kernel (r7's proven body; sedge int2 input) ----------
// Per wave: 64 edges (4 groups of 16). All LDS traffic is wave-local.
// ub row (208B): chunks 0..11 = ef(96 f16); then chunks 0..7 overwritten by
// h(64 f16), chunks 8..11 by sh/v1 f32 stash (after eff hoist); finally
// chunks 0..6 overwritten by msg(28 f32).
__global__ __launch_bounds__(256, 2) void tfn_mfma_kernel(
    const float* __restrict__ node_attr, const float* __restrict__ pos,
    const float* __restrict__ b1, const float* __restrict__ b2,
    const char* __restrict__ img1, const char* __restrict__ img2,
    const int2* __restrict__ sedge, float* __restrict__ agg, int E) {
  __shared__ __align__(16) char ub[256 * kRowB];   // 53248 B
  __shared__ __align__(16) char ax[256 * kAuxB];   // 12288 B

  const int tid = threadIdx.x;
  const int t = blockIdx.x * 256 + tid;
  const int lane = tid & 63;
  const int wv = tid >> 6;
  const int lc = lane & 15, lq = lane >> 4;

  const bool valid = (t < E);
  int src = 0, dstv = -1;
  if (valid) {
    const int2 se = sedge[t];
    src = se.x;
    dstv = se.y;
  }
  const int dn = valid ? dstv : 0;

  // ---- geometry ----
  const float psx = pos[src * 3 + 0], psy = pos[src * 3 + 1], psz = pos[src * 3 + 2];
  const float pdx = pos[dn * 3 + 0], pdy = pos[dn * 3 + 1], pdz = pos[dn * 3 + 2];
  const float vx = pdx - psx, vy = pdy - psy, vz = pdz - psz;
  const float dist = sqrtf(vx * vx + vy * vy + vz * vz);
  const float rinv = 1.0f / fmaxf(dist, 1e-8f);
  const float sh0 = kSqrt3 * (vy * rinv);
  const float sh1 = kSqrt3 * (vz * rinv);
  const float sh2 = kSqrt3 * (vx * rinv);

  const float* nas = node_attr + (size_t)src * kAttr;
  const float* nad = node_attr + (size_t)dn * kAttr;
  const float4 sa = *(const float4*)(nas + 0);
  const float4 sb = *(const float4*)(nas + 4);
  const float4 sc4 = *(const float4*)(nas + 8);
  const float4 sd4 = *(const float4*)(nas + 12);
  const float4 va = *(const float4*)(nas + 16);
  const float4 vb = *(const float4*)(nas + 20);
  const float4 vc = *(const float4*)(nas + 24);
  const float4 da = *(const float4*)(nad + 0);
  const float4 db = *(const float4*)(nad + 4);
  const float4 dc4 = *(const float4*)(nad + 8);
  const float4 dd4 = *(const float4*)(nad + 12);

  char* myrow = ub + tid * kRowB;

  // ---- write ef row (96 f16): [gauss50 | 0x6 | ss16 | ds16 | 0x8] ----
  {
    const float base = dist + 1e-6f;
#pragma unroll
    for (int c = 0; c < 6; ++c) {
      unsigned p[4];
#pragma unroll
      for (int u = 0; u < 4; ++u) {
        const int k = c * 8 + u * 2;
        const float d0 = base - (float)k * kStep;
        const float d1 = base - (float)(k + 1) * kStep;
        p[u] = pack2(__expf(kCoeff * d0 * d0), __expf(kCoeff * d1 * d1));
      }
      *(u32x4*)(myrow + c * 16) = u32x4{p[0], p[1], p[2], p[3]};
    }
    const float d0 = base - 48.0f * kStep, d1 = base - 49.0f * kStep;
    *(u32x4*)(myrow + 6 * 16) =
        u32x4{pack2(__expf(kCoeff * d0 * d0), __expf(kCoeff * d1 * d1)), 0u, 0u, 0u};
    *(u32x4*)(myrow + 7 * 16) =
        u32x4{pack2(sa.x, sa.y), pack2(sa.z, sa.w), pack2(sb.x, sb.y), pack2(sb.z, sb.w)};
    *(u32x4*)(myrow + 8 * 16) =
        u32x4{pack2(sc4.x, sc4.y), pack2(sc4.z, sc4.w), pack2(sd4.x, sd4.y), pack2(sd4.z, sd4.w)};
    *(u32x4*)(myrow + 9 * 16) =
        u32x4{pack2(da.x, da.y), pack2(da.z, da.w), pack2(db.x, db.y), pack2(db.z, db.w)};
    *(u32x4*)(myrow + 10 * 16) =
        u32x4{pack2(dc4.x, dc4.y), pack2(dc4.z, dc4.w), pack2(dd4.x, dd4.y), pack2(dd4.z, dd4.w)};
    *(u32x4*)(myrow + 11 * 16) = u32x4{0u, 0u, 0u, 0u};
  }

  // ---- aux row: o0[20] as f16 ----
  const float v1f[12] = {va.x, va.y, va.z, va.w, vb.x, vb.y, vb.z, vb.w,
                         vc.x, vc.y, vc.z, vc.w};
  {
    const float t0 = (v1f[0] * sh0 + v1f[1] * sh1 + v1f[2] * sh2) * kInvSqrt3;
    const float t1 = (v1f[3] * sh0 + v1f[4] * sh1 + v1f[5] * sh2) * kInvSqrt3;
    const float t2 = (v1f[6] * sh0 + v1f[7] * sh1 + v1f[8] * sh2) * kInvSqrt3;
    const float t3 = (v1f[9] * sh0 + v1f[10] * sh1 + v1f[11] * sh2) * kInvSqrt3;
    char* myax = ax + tid * kAuxB;
    *(u32x4*)(myax + 0) = u32x4{pack2(sa.x, sa.y), pack2(sa.z, sa.w),
                                pack2(sb.x, sb.y), pack2(sb.z, sb.w)};
    *(u32x4*)(myax + 16) = u32x4{pack2(sc4.x, sc4.y), pack2(sc4.z, sc4.w),
                                 pack2(sd4.x, sd4.y), pack2(sd4.z, sd4.w)};
    *(u32x2*)(myax + 32) = u32x2{pack2(t0, t1), pack2(t2, t3)};
  }

  // ---- hoist ef fragments (B-operand: lane holds ef[e=g*16+lc][k=(ks*4+lq)*8+j]) ----
  half8 eff[4][3];
#pragma unroll
  for (int g = 0; g < 4; ++g) {
    const char* rp = ub + (wv * 64 + g * 16 + lc) * kRowB;
#pragma unroll
    for (int ks = 0; ks < 3; ++ks)
      eff[g][ks] = *(const half8*)(rp + (ks * 4 + lq) * 16);
  }

  // ---- stash sh/v1 as f32 into chunks 8..11 (ef chunks 8..11 now dead) ----
  *(f32x4*)(myrow + 8 * 16) = f32x4{sh0, sh1, sh2, v1f[0]};
  *(f32x4*)(myrow + 9 * 16) = f32x4{v1f[1], v1f[2], v1f[3], v1f[4]};
  *(f32x4*)(myrow + 10 * 16) = f32x4{v1f[5], v1f[6], v1f[7], v1f[8]};
  *(f32x4*)(myrow + 11 * 16) = f32x4{v1f[9], v1f[10], v1f[11], 0.0f};

  // ---- MFMA-1: h[n][e] = relu(b1[n] + sum_k W1p[k][n] ef[e][k]) ----
#pragma unroll
  for (int nt = 0; nt < 4; ++nt) {
    const half8 a0 = *(const half8*)(img1 + ((0 + lq) * 64 + nt * 16 + lc) * 16);
    const half8 a1 = *(const half8*)(img1 + ((4 + lq) * 64 + nt * 16 + lc) * 16);
    const half8 a2 = *(const half8*)(img1 + ((8 + lq) * 64 + nt * 16 + lc) * 16);
    const f32x4 bias = *(const f32x4*)(b1 + nt * 16 + lq * 4);
#pragma unroll
    for (int g = 0; g < 4; ++g) {
      f32x4 acc = bias;
      acc = __builtin_amdgcn_mfma_f32_16x16x32_f16(a0, eff[g][0], acc, 0, 0, 0);
      acc = __builtin_amdgcn_mfma_f32_16x16x32_f16(a1, eff[g][1], acc, 0, 0, 0);
      acc = __builtin_amdgcn_mfma_f32_16x16x32_f16(a2, eff[g][2], acc, 0, 0, 0);
      const unsigned p0 = pack2(fmaxf(acc[0], 0.0f), fmaxf(acc[1], 0.0f));
      const unsigned p1 = pack2(fmaxf(acc[2], 0.0f), fmaxf(acc[3], 0.0f));
      const int row = wv * 64 + g * 16 + lc;
      // n = nt*16 + lq*4 + r -> byte 2n = nt*32 + lq*8
      *(u32x2*)(ub + row * kRowB + nt * 32 + lq * 8) = u32x2{p0, p1};
    }
  }

  // ---- load h fragments (B-operand: lane holds h[k][e=g*16+lc]) ----
  half8 hf[4][2];
#pragma unroll
  for (int g = 0; g < 4; ++g) {
    const char* rp = ub + (wv * 64 + g * 16 + lc) * kRowB;
    hf[g][0] = *(const half8*)(rp + (0 + lq) * 16);
    hf[g][1] = *(const half8*)(rp + (4 + lq) * 16);
  }

  // ---- hoist per-edge sh / v1 (lane owns edge lc of each group) ----
  float shv[4][3], v1h[4][3];
#pragma unroll
  for (int g = 0; g < 4; ++g) {
    const char* rp = ub + (wv * 64 + g * 16 + lc) * kRowB;
#pragma unroll
    for (int c = 0; c < 3; ++c) {
      shv[g][c] = *(const float*)(rp + 128 + 4 * c);
      v1h[g][c] = *(const float*)(rp + 140 + 12 * lq + 4 * c);
    }
  }

  // ---- MFMA-2 + fused contraction. D[n][e]: lane owns edge lc, n = 16nt+4lq+r ----
  float macc0[4][4] = {};
  float macc1[4][4][3] = {};

#pragma unroll 5
  for (int nt = 0; nt < 20; ++nt) {
    const half8 w0 = *(const half8*)(img2 + ((0 + lq) * 400 + nt * 16 + lc) * 16);
    const half8 w1 = *(const half8*)(img2 + ((4 + lq) * 400 + nt * 16 + lc) * 16);
    const f32x4 bias = *(const f32x4*)(b2 + nt * 16 + lq * 4);
#pragma unroll
    for (int g = 0; g < 4; ++g) {
      f32x4 acc = bias;
      acc = __builtin_amdgcn_mfma_f32_16x16x32_f16(w0, hf[g][0], acc, 0, 0, 0);
      acc = __builtin_amdgcn_mfma_f32_16x16x32_f16(w1, hf[g][1], acc, 0, 0, 0);
      const int row = wv * 64 + g * 16 + lc;
      const float o0v = h2f(*(const unsigned short*)(ax + row * kAuxB + 2 * nt));
#pragma unroll
      for (int r = 0; r < 4; ++r) macc0[g][r] = fmaf(o0v, acc[r], macc0[g][r]);
    }
  }
#pragma unroll
  for (int nt = 20; nt < 24; ++nt) {
    const half8 w0 = *(const half8*)(img2 + ((0 + lq) * 400 + nt * 16 + lc) * 16);
    const half8 w1 = *(const half8*)(img2 + ((4 + lq) * 400 + nt * 16 + lc) * 16);
    const f32x4 bias = *(const f32x4*)(b2 + nt * 16 + lq * 4);
#pragma unroll
    for (int g = 0; g < 4; ++g) {
      f32x4 acc = bias;
      acc = __builtin_amdgcn_mfma_f32_16x16x32_f16(w0, hf[g][0], acc, 0, 0, 0);
      acc = __builtin_amdgcn_mfma_f32_16x16x32_f16(w1, hf[g][1], acc, 0, 0, 0);
      const int row = wv * 64 + g * 16 + lc;
      // i = 4*(nt-20) + lq, o = r; o1[i] = ss[i] * sh
      const float ssv =
          h2f(*(const unsigned short*)(ax + row * kAuxB + 2 * (4 * (nt - 20) + lq)));
      float pc[3];
#pragma unroll
      for (int c = 0; c < 3; ++c) pc[c] = ssv * shv[g][c];
#pragma unroll
      for (int r = 0; r < 4; ++r)
#pragma unroll
        for (int c = 0; c < 3; ++c)
          macc1[g][r][c] = fmaf(pc[c], acc[r], macc1[g][r][c]);
    }
  }
  {  // nt = 24: i = 16 + lq, o1 row = in_1o
    const int nt = 24;
    const half8 w0 = *(const half8*)(img2 + ((0 + lq) * 400 + nt * 16 + lc) * 16);
    const half8 w1 = *(const half8*)(img2 + ((4 + lq) * 400 + nt * 16 + lc) * 16);
    const f32x4 bias = *(const f32x4*)(b2 + nt * 16 + lq * 4);
#pragma unroll
    for (int g = 0; g < 4; ++g) {
      f32x4 acc = bias;
      acc = __builtin_amdgcn_mfma_f32_16x16x32_f16(w0, hf[g][0], acc, 0, 0, 0);
      acc = __builtin_amdgcn_mfma_f32_16x16x32_f16(w1, hf[g][1], acc, 0, 0, 0);
#pragma unroll
      for (int r = 0; r < 4; ++r)
#pragma unroll
        for (int c = 0; c < 3; ++c)
          macc1[g][r][c] = fmaf(v1h[g][c], acc[r], macc1[g][r][c]);
    }
  }

  // ---- finish msg1 (reduce i-partition across lq groups), scale, write msg rows ----
#pragma unroll
  for (int g = 0; g < 4; ++g)
#pragma unroll
    for (int r = 0; r < 4; ++r)
#pragma unroll
      for (int c = 0; c < 3; ++c) {
        float x = macc1[g][r][c];
        x += __shfl_xor(x, 16);
        x += __shfl_xor(x, 32);
        macc1[g][r][c] = x * kInvSqrt20;
      }
#pragma unroll
  for (int g = 0; g < 4; ++g) {
    char* rp = ub + (wv * 64 + g * 16 + lc) * kRowB;
    *(f32x4*)(rp + lq * 16) =
        f32x4{macc0[g][0] * kInvSqrt20, macc0[g][1] * kInvSqrt20,
              macc0[g][2] * kInvSqrt20, macc0[g][3] * kInvSqrt20};
    f32x4 m1;
    if (lq == 1)
      m1 = f32x4{macc1[g][0][0], macc1[g][0][1], macc1[g][0][2], macc1[g][1][0]};
    else if (lq == 2)
      m1 = f32x4{macc1[g][1][1], macc1[g][1][2], macc1[g][2][0], macc1[g][2][1]};
    else
      m1 = f32x4{macc1[g][2][2], macc1[g][3][0], macc1[g][3][1], macc1[g][3][2]};
    if (lq != 0) *(f32x4*)(rp + 48 + lq * 16) = m1;
  }

  // ---- read back own msg, segmented wave reduction, one atomic per segment head ----
  float msg[28];
  {
    const char* rp = ub + tid * kRowB;
#pragma unroll
    for (int c = 0; c < 7; ++c) {
      const f32x4 v = *(const f32x4*)(rp + c * 16);
      msg[c * 4 + 0] = v[0];
      msg[c * 4 + 1] = v[1];
      msg[c * 4 + 2] = v[2];
      msg[c * 4 + 3] = v[3];
    }
  }
#pragma unroll
  for (int d = 1; d < 64; d <<= 1) {
    const int od = __shfl_down(dstv, d);
    const bool same = (lane + d < 64) && (od == dstv);
#pragma unroll
    for (int j = 0; j < 28; j++) {
      const float ov = __shfl_down(msg[j], d);
      if (same) msg[j] += ov;
    }
  }
  const int pd = __shfl_up(dstv, 1);
  if ((lane == 0 || pd != dstv) && dstv >= 0) {
    float* ap = agg + (size_t)dstv * kAttr;
#pragma unroll
    for (int j = 0; j < 28; j++) atomicAdd(ap + j, msg[j]);
  }
}

__global__ __launch_bounds__(256) void tfn_finalize_kernel(
    const float* __restrict__ node_attr, const int* __restrict__ cnt,
    float* __restrict__ out, int total) {
  const int i = blockIdx.x * blockDim.x + threadIdx.x;
  if (i >= total) return;
  const int n = i / kAttr;
  const float c = fmaxf((float)cnt[n], 1.0f);
  out[i] = node_attr[i] + out[i] / c;
}

extern "C" void kernel_launch(void* const* d_in, const int* in_sizes, int n_in,
                              void* d_out, int out_size, void* d_ws, size_t ws_size,
                              hipStream_t stream) {
  const float* node_attr = (const float*)d_in[0];
  const float* pos = (const float*)d_in[1];
  const float* W1 = (const float*)d_in[2];
  const float* b1 = (const float*)d_in[3];
  const float* W2 = (const float*)d_in[4];
  const float* b2 = (const float*)d_in[5];
  const int* edge_index = (const int*)d_in[6];

  const int N = in_sizes[0] / kAttr;
  const int E = in_sizes[6] / 2;

  // ws layout: [img1 12288B][img2 51200B][cnt N][cur N][sedge E int2] ~ 2.7MB
  char* wsc = (char*)d_ws;
  unsigned short* img1 = (unsigned short*)wsc;
  unsigned short* img2 = (unsigned short*)(wsc + kImg1Bytes);
  int* cnt = (int*)(wsc + kImg1Bytes + kImg2Bytes);
  int* cur = cnt + N;
  int2* sedge = (int2*)(cur + N);

  float* agg = (float*)d_out;
  int aggN4 = out_size / 4;
  const int eblocks = (E + 255) / 256;
  const int total = N * kAttr;

  void* args[] = {(void*)&W1, (void*)&W2, (void*)&img1, (void*)&img2,
                  (void*)&edge_index, (void*)&cnt, (void*)&cur,
                  (void*)&sedge, (void*)&agg, (void*)&aggN4,
                  (void*)&N, (void*)&E};

  // Sort kernel is LDS-light (1KB) -> 8 blocks/CU co-residency -> up to 2048
  // cooperative blocks. Cascade down if the runtime refuses.
  hipError_t err = hipLaunchCooperativeKernel((const void*)coop_sort_kernel,
                                              dim3(2048), dim3(256), args, 0, stream);
  if (err != hipSuccess)
    err = hipLaunchCooperativeKernel((const void*)coop_sort_kernel,
                                     dim3(1024), dim3(256), args, 0, stream);
  if (err != hipSuccess)
    (void)hipLaunchCooperativeKernel((const void*)coop_sort_kernel,
                                     dim3(512), dim3(256), args, 0, stream);

  tfn_mfma_kernel<<<eblocks, 256, 0, stream>>>(
      node_attr, pos, b1, b2, (const char*)img1, (const char*)img2,
      sedge, agg, E);

  tfn_finalize_kernel<<<(total + 255) / 256, 256, 0, stream>>>(
      node_attr, cnt, (float*)d_out, total);
}

// Round 10
// 138.685 us; speedup vs baseline: 4.3958x; 4.3958x over previous
//
#include <hip/hip_runtime.h>
#include <math.h>

typedef _Float16 half8 __attribute__((ext_vector_type(8)));
typedef float f32x4 __attribute__((ext_vector_type(4)));
typedef unsigned int u32x4 __attribute__((ext_vector_type(4)));
typedef unsigned int u32x2 __attribute__((ext_vector_type(2)));

namespace {
constexpr int kNS = 16;
constexpr int kNV = 4;
constexpr int kNG = 50;
constexpr int kHID = 64;
constexpr int kAttr = 28;                 // NS + 3*NV
constexpr int kWNUM = 400;
constexpr float kStep = 5.0f / 49.0f;
constexpr float kCoeff = -0.5f / (kStep * kStep);
constexpr float kSqrt3 = 1.7320508075688772f;
constexpr float kInvSqrt3 = 0.57735026918962576f;
constexpr float kInvSqrt20 = 0.22360679774997896f;
// Row = 208 B (13 granules): 52 words == 20 mod 32 -> 16 rows spread over 8
// bank-offset classes (2 lanes/bank = free). No XOR swizzle (r3 lesson).
constexpr int kRowB = 208;
constexpr int kAuxB = 48;                 // aux row: 20 f16 o0 (+pad)
constexpr int kImg1Bytes = 96 * 64 * 2;   // 12288
constexpr int kImg2Bytes = 64 * 400 * 2;  // 51200
}  // namespace

// f16 end-to-end (r6-r9: absmax 0.06-0.09 vs threshold 0.101; bf16 too thin).
// (_Float16) cast = hardware v_cvt_f16_f32 RNE (r5: hip bf16 helpers truncate).
__device__ __forceinline__ unsigned short f2h(float x) {
  _Float16 h = (_Float16)x;
  unsigned short r;
  __builtin_memcpy(&r, &h, 2);
  return r;
}
__device__ __forceinline__ unsigned pack2(float lo, float hi) {
  return (unsigned)f2h(lo) | ((unsigned)f2h(hi) << 16);
}
__device__ __forceinline__ float h2f(unsigned short v) {
  _Float16 h;
  __builtin_memcpy(&h, &v, 2);
  return (float)h;
}

// ---------- A: fused init (zero agg + zero cnt + f16 weight images) ----------
// r9 lesson: NO cooperative grid.sync (537us of spin at 2048 blocks). Plain
// dispatches provide the ordering; r4 proved each aux phase <9us at high
// occupancy. This kernel fuses the two memsets + prep = 3 dispatches -> 1.
__global__ __launch_bounds__(256) void init_kernel(
    const float* __restrict__ W1, const float* __restrict__ W2,
    unsigned short* __restrict__ img1, unsigned short* __restrict__ img2,
    int* __restrict__ cnt, float* __restrict__ agg, int aggN4, int N) {
  const int gtid = blockIdx.x * 256 + threadIdx.x;
  const int gsz = gridDim.x * 256;
  f32x4* agg4 = (f32x4*)agg;
  for (int i = gtid; i < aggN4; i += gsz) agg4[i] = f32x4{0.f, 0.f, 0.f, 0.f};
  for (int i = gtid; i < N; i += gsz) cnt[i] = 0;
  // img layout: element (k, n) at byte ((k>>3)*W + n)*16 + 2*(k&7)
  for (int i = gtid; i < 96 * 64 + 64 * 400; i += gsz) {
    if (i < 96 * 64) {
      const int m = i >> 6, n = i & 63;
      float v = 0.0f;
      if (m < 50) v = W1[m * 64 + n];                        // gaussian rows
      else if (m >= 56 && m < 88) v = W1[(m - 6) * 64 + n];  // ss, ds rows
      img1[((m >> 3) * 64 + n) * 8 + (m & 7)] = f2h(v);
    } else {
      const int j = i - 96 * 64;
      const int m = j / 400, n = j % 400;
      img2[((m >> 3) * 400 + n) * 8 + (m & 7)] = f2h(W2[m * 400 + n]);
    }
  }
}

// ---------- B: histogram of dst ----------
__global__ __launch_bounds__(256) void hist_kernel(
    const int* __restrict__ edge_index, int* __restrict__ cnt, int E) {
  const int e = blockIdx.x * blockDim.x + threadIdx.x;
  if (e >= E) return;
  atomicAdd(cnt + edge_index[E + e], 1);
}

// ---------- C: exclusive scan cnt -> cur (single block; r4-proven) ----------
__global__ __launch_bounds__(256) void scan_kernel(
    const int* __restrict__ cnt, int* __restrict__ cur, int N) {
  __shared__ int sums[256];
  const int tid = threadIdx.x;
  const int chunk = (N + 255) / 256;
  const int base = tid * chunk;
  int s = 0;
  for (int j = 0; j < chunk; j++) {
    const int i = base + j;
    if (i < N) s += cnt[i];
  }
  sums[tid] = s;
  __syncthreads();
  for (int d = 1; d < 256; d <<= 1) {
    const int y = (tid >= d) ? sums[tid - d] : 0;
    __syncthreads();
    sums[tid] += y;
    __syncthreads();
  }
  int run = sums[tid] - s;
  for (int j = 0; j < chunk; j++) {
    const int i = base + j;
    if (i < N) { cur[i] = run; run += cnt[i]; }
  }
}

// ---------- D: scatter into dst-sorted order (fused int2 records) ----------
__global__ __launch_bounds__(256) void scatter_kernel(
    const int* __restrict__ edge_index, int* __restrict__ cur,
    int2* __restrict__ sedge, int E) {
  const int e = blockIdx.x * blockDim.x + threadIdx.x;
  if (e >= E) return;
  const int s = edge_index[e];
  const int d = edge_index[E + e];
  const int p = atomicAdd(cur + d, 1);
  sedge[p] = int2{s, d};
}

// ---------- E: main MFMA edge kernel (r7/r9-proven body) ----------
// Per wave: 64 edges (4 groups of 16). All LDS traffic is wave-local.
// ub row (208B): chunks 0..11 = ef(96 f16); then chunks 0..7 overwritten by
// h(64 f16), chunks 8..11 by sh/v1 f32 stash (after eff hoist); finally
// chunks 0..6 overwritten by msg(28 f32).
__global__ __launch_bounds__(256, 2) void tfn_mfma_kernel(
    const float* __restrict__ node_attr, const float* __restrict__ pos,
    const float* __restrict__ b1, const float* __restrict__ b2,
    const char* __restrict__ img1, const char* __restrict__ img2,
    const int2* __restrict__ sedge, float* __restrict__ agg, int E) {
  __shared__ __align__(16) char ub[256 * kRowB];   // 53248 B
  __shared__ __align__(16) char ax[256 * kAuxB];   // 12288 B

  const int tid = threadIdx.x;
  const int t = blockIdx.x * 256 + tid;
  const int lane = tid & 63;
  const int wv = tid >> 6;
  const int lc = lane & 15, lq = lane >> 4;

  const bool valid = (t < E);
  int src = 0, dstv = -1;
  if (valid) {
    const int2 se = sedge[t];
    src = se.x;
    dstv = se.y;
  }
  const int dn = valid ? dstv : 0;

  // ---- geometry ----
  const float psx = pos[src * 3 + 0], psy = pos[src * 3 + 1], psz = pos[src * 3 + 2];
  const float pdx = pos[dn * 3 + 0], pdy = pos[dn * 3 + 1], pdz = pos[dn * 3 + 2];
  const float vx = pdx - psx, vy = pdy - psy, vz = pdz - psz;
  const float dist = sqrtf(vx * vx + vy * vy + vz * vz);
  const float rinv = 1.0f / fmaxf(dist, 1e-8f);
  const float sh0 = kSqrt3 * (vy * rinv);
  const float sh1 = kSqrt3 * (vz * rinv);
  const float sh2 = kSqrt3 * (vx * rinv);

  const float* nas = node_attr + (size_t)src * kAttr;
  const float* nad = node_attr + (size_t)dn * kAttr;
  const float4 sa = *(const float4*)(nas + 0);
  const float4 sb = *(const float4*)(nas + 4);
  const float4 sc4 = *(const float4*)(nas + 8);
  const float4 sd4 = *(const float4*)(nas + 12);
  const float4 va = *(const float4*)(nas + 16);
  const float4 vb = *(const float4*)(nas + 20);
  const float4 vc = *(const float4*)(nas + 24);
  const float4 da = *(const float4*)(nad + 0);
  const float4 db = *(const float4*)(nad + 4);
  const float4 dc4 = *(const float4*)(nad + 8);
  const float4 dd4 = *(const float4*)(nad + 12);

  char* myrow = ub + tid * kRowB;

  // ---- write ef row (96 f16): [gauss50 | 0x6 | ss16 | ds16 | 0x8] ----
  {
    const float base = dist + 1e-6f;
#pragma unroll
    for (int c = 0; c < 6; ++c) {
      unsigned p[4];
#pragma unroll
      for (int u = 0; u < 4; ++u) {
        const int k = c * 8 + u * 2;
        const float d0 = base - (float)k * kStep;
        const float d1 = base - (float)(k + 1) * kStep;
        p[u] = pack2(__expf(kCoeff * d0 * d0), __expf(kCoeff * d1 * d1));
      }
      *(u32x4*)(myrow + c * 16) = u32x4{p[0], p[1], p[2], p[3]};
    }
    const float d0 = base - 48.0f * kStep, d1 = base - 49.0f * kStep;
    *(u32x4*)(myrow + 6 * 16) =
        u32x4{pack2(__expf(kCoeff * d0 * d0), __expf(kCoeff * d1 * d1)), 0u, 0u, 0u};
    *(u32x4*)(myrow + 7 * 16) =
        u32x4{pack2(sa.x, sa.y), pack2(sa.z, sa.w), pack2(sb.x, sb.y), pack2(sb.z, sb.w)};
    *(u32x4*)(myrow + 8 * 16) =
        u32x4{pack2(sc4.x, sc4.y), pack2(sc4.z, sc4.w), pack2(sd4.x, sd4.y), pack2(sd4.z, sd4.w)};
    *(u32x4*)(myrow + 9 * 16) =
        u32x4{pack2(da.x, da.y), pack2(da.z, da.w), pack2(db.x, db.y), pack2(db.z, db.w)};
    *(u32x4*)(myrow + 10 * 16) =
        u32x4{pack2(dc4.x, dc4.y), pack2(dc4.z, dc4.w), pack2(dd4.x, dd4.y), pack2(dd4.z, dd4.w)};
    *(u32x4*)(myrow + 11 * 16) = u32x4{0u, 0u, 0u, 0u};
  }

  // ---- aux row: o0[20] as f16 ----
  const float v1f[12] = {va.x, va.y, va.z, va.w, vb.x, vb.y, vb.z, vb.w,
                         vc.x, vc.y, vc.z, vc.w};
  {
    const float t0 = (v1f[0] * sh0 + v1f[1] * sh1 + v1f[2] * sh2) * kInvSqrt3;
    const float t1 = (v1f[3] * sh0 + v1f[4] * sh1 + v1f[5] * sh2) * kInvSqrt3;
    const float t2 = (v1f[6] * sh0 + v1f[7] * sh1 + v1f[8] * sh2) * kInvSqrt3;
    const float t3 = (v1f[9] * sh0 + v1f[10] * sh1 + v1f[11] * sh2) * kInvSqrt3;
    char* myax = ax + tid * kAuxB;
    *(u32x4*)(myax + 0) = u32x4{pack2(sa.x, sa.y), pack2(sa.z, sa.w),
                                pack2(sb.x, sb.y), pack2(sb.z, sb.w)};
    *(u32x4*)(myax + 16) = u32x4{pack2(sc4.x, sc4.y), pack2(sc4.z, sc4.w),
                                 pack2(sd4.x, sd4.y), pack2(sd4.z, sd4.w)};
    *(u32x2*)(myax + 32) = u32x2{pack2(t0, t1), pack2(t2, t3)};
  }

  // ---- hoist ef fragments (B-operand: lane holds ef[e=g*16+lc][k=(ks*4+lq)*8+j]) ----
  half8 eff[4][3];
#pragma unroll
  for (int g = 0; g < 4; ++g) {
    const char* rp = ub + (wv * 64 + g * 16 + lc) * kRowB;
#pragma unroll
    for (int ks = 0; ks < 3; ++ks)
      eff[g][ks] = *(const half8*)(rp + (ks * 4 + lq) * 16);
  }

  // ---- stash sh/v1 as f32 into chunks 8..11 (ef chunks 8..11 now dead) ----
  *(f32x4*)(myrow + 8 * 16) = f32x4{sh0, sh1, sh2, v1f[0]};
  *(f32x4*)(myrow + 9 * 16) = f32x4{v1f[1], v1f[2], v1f[3], v1f[4]};
  *(f32x4*)(myrow + 10 * 16) = f32x4{v1f[5], v1f[6], v1f[7], v1f[8]};
  *(f32x4*)(myrow + 11 * 16) = f32x4{v1f[9], v1f[10], v1f[11], 0.0f};

  // ---- MFMA-1: h[n][e] = relu(b1[n] + sum_k W1p[k][n] ef[e][k]) ----
#pragma unroll
  for (int nt = 0; nt < 4; ++nt) {
    const half8 a0 = *(const half8*)(img1 + ((0 + lq) * 64 + nt * 16 + lc) * 16);
    const half8 a1 = *(const half8*)(img1 + ((4 + lq) * 64 + nt * 16 + lc) * 16);
    const half8 a2 = *(const half8*)(img1 + ((8 + lq) * 64 + nt * 16 + lc) * 16);
    const f32x4 bias = *(const f32x4*)(b1 + nt * 16 + lq * 4);
#pragma unroll
    for (int g = 0; g < 4; ++g) {
      f32x4 acc = bias;
      acc = __builtin_amdgcn_mfma_f32_16x16x32_f16(a0, eff[g][0], acc, 0, 0, 0);
      acc = __builtin_amdgcn_mfma_f32_16x16x32_f16(a1, eff[g][1], acc, 0, 0, 0);
      acc = __builtin_amdgcn_mfma_f32_16x16x32_f16(a2, eff[g][2], acc, 0, 0, 0);
      const unsigned p0 = pack2(fmaxf(acc[0], 0.0f), fmaxf(acc[1], 0.0f));
      const unsigned p1 = pack2(fmaxf(acc[2], 0.0f), fmaxf(acc[3], 0.0f));
      const int row = wv * 64 + g * 16 + lc;
      // n = nt*16 + lq*4 + r -> byte 2n = nt*32 + lq*8
      *(u32x2*)(ub + row * kRowB + nt * 32 + lq * 8) = u32x2{p0, p1};
    }
  }

  // ---- load h fragments (B-operand: lane holds h[k][e=g*16+lc]) ----
  half8 hf[4][2];
#pragma unroll
  for (int g = 0; g < 4; ++g) {
    const char* rp = ub + (wv * 64 + g * 16 + lc) * kRowB;
    hf[g][0] = *(const half8*)(rp + (0 + lq) * 16);
    hf[g][1] = *(const half8*)(rp + (4 + lq) * 16);
  }

  // ---- hoist per-edge sh / v1 (lane owns edge lc of each group) ----
  float shv[4][3], v1h[4][3];
#pragma unroll
  for (int g = 0; g < 4; ++g) {
    const char* rp = ub + (wv * 64 + g * 16 + lc) * kRowB;
#pragma unroll
    for (int c = 0; c < 3; ++c) {
      shv[g][c] = *(const float*)(rp + 128 + 4 * c);
      v1h[g][c] = *(const float*)(rp + 140 + 12 * lq + 4 * c);
    }
  }

  // ---- MFMA-2 + fused contraction. D[n][e]: lane owns edge lc, n = 16nt+4lq+r ----
  float macc0[4][4] = {};
  float macc1[4][4][3] = {};

#pragma unroll 5
  for (int nt = 0; nt < 20; ++nt) {
    const half8 w0 = *(const half8*)(img2 + ((0 + lq) * 400 + nt * 16 + lc) * 16);
    const half8 w1 = *(const half8*)(img2 + ((4 + lq) * 400 + nt * 16 + lc) * 16);
    const f32x4 bias = *(const f32x4*)(b2 + nt * 16 + lq * 4);
#pragma unroll
    for (int g = 0; g < 4; ++g) {
      f32x4 acc = bias;
      acc = __builtin_amdgcn_mfma_f32_16x16x32_f16(w0, hf[g][0], acc, 0, 0, 0);
      acc = __builtin_amdgcn_mfma_f32_16x16x32_f16(w1, hf[g][1], acc, 0, 0, 0);
      const int row = wv * 64 + g * 16 + lc;
      const float o0v = h2f(*(const unsigned short*)(ax + row * kAuxB + 2 * nt));
#pragma unroll
      for (int r = 0; r < 4; ++r) macc0[g][r] = fmaf(o0v, acc[r], macc0[g][r]);
    }
  }
#pragma unroll
  for (int nt = 20; nt < 24; ++nt) {
    const half8 w0 = *(const half8*)(img2 + ((0 + lq) * 400 + nt * 16 + lc) * 16);
    const half8 w1 = *(const half8*)(img2 + ((4 + lq) * 400 + nt * 16 + lc) * 16);
    const f32x4 bias = *(const f32x4*)(b2 + nt * 16 + lq * 4);
#pragma unroll
    for (int g = 0; g < 4; ++g) {
      f32x4 acc = bias;
      acc = __builtin_amdgcn_mfma_f32_16x16x32_f16(w0, hf[g][0], acc, 0, 0, 0);
      acc = __builtin_amdgcn_mfma_f32_16x16x32_f16(w1, hf[g][1], acc, 0, 0, 0);
      const int row = wv * 64 + g * 16 + lc;
      // i = 4*(nt-20) + lq, o = r; o1[i] = ss[i] * sh
      const float ssv =
          h2f(*(const unsigned short*)(ax + row * kAuxB + 2 * (4 * (nt - 20) + lq)));
      float pc[3];
#pragma unroll
      for (int c = 0; c < 3; ++c) pc[c] = ssv * shv[g][c];
#pragma unroll
      for (int r = 0; r < 4; ++r)
#pragma unroll
        for (int c = 0; c < 3; ++c)
          macc1[g][r][c] = fmaf(pc[c], acc[r], macc1[g][r][c]);
    }
  }
  {  // nt = 24: i = 16 + lq, o1 row = in_1o
    const int nt = 24;
    const half8 w0 = *(const half8*)(img2 + ((0 + lq) * 400 + nt * 16 + lc) * 16);
    const half8 w1 = *(const half8*)(img2 + ((4 + lq) * 400 + nt * 16 + lc) * 16);
    const f32x4 bias = *(const f32x4*)(b2 + nt * 16 + lq * 4);
#pragma unroll
    for (int g = 0; g < 4; ++g) {
      f32x4 acc = bias;
      acc = __builtin_amdgcn_mfma_f32_16x16x32_f16(w0, hf[g][0], acc, 0, 0, 0);
      acc = __builtin_amdgcn_mfma_f32_16x16x32_f16(w1, hf[g][1], acc, 0, 0, 0);
#pragma unroll
      for (int r = 0; r < 4; ++r)
#pragma unroll
        for (int c = 0; c < 3; ++c)
          macc1[g][r][c] = fmaf(v1h[g][c], acc[r], macc1[g][r][c]);
    }
  }

  // ---- finish msg1 (reduce i-partition across lq groups), scale, write msg rows ----
#pragma unroll
  for (int g = 0; g < 4; ++g)
#pragma unroll
    for (int r = 0; r < 4; ++r)
#pragma unroll
      for (int c = 0; c < 3; ++c) {
        float x = macc1[g][r][c];
        x += __shfl_xor(x, 16);
        x += __shfl_xor(x, 32);
        macc1[g][r][c] = x * kInvSqrt20;
      }
#pragma unroll
  for (int g = 0; g < 4; ++g) {
    char* rp = ub + (wv * 64 + g * 16 + lc) * kRowB;
    *(f32x4*)(rp + lq * 16) =
        f32x4{macc0[g][0] * kInvSqrt20, macc0[g][1] * kInvSqrt20,
              macc0[g][2] * kInvSqrt20, macc0[g][3] * kInvSqrt20};
    f32x4 m1;
    if (lq == 1)
      m1 = f32x4{macc1[g][0][0], macc1[g][0][1], macc1[g][0][2], macc1[g][1][0]};
    else if (lq == 2)
      m1 = f32x4{macc1[g][1][1], macc1[g][1][2], macc1[g][2][0], macc1[g][2][1]};
    else
      m1 = f32x4{macc1[g][2][2], macc1[g][3][0], macc1[g][3][1], macc1[g][3][2]};
    if (lq != 0) *(f32x4*)(rp + 48 + lq * 16) = m1;
  }

  // ---- read back own msg, segmented wave reduction, one atomic per segment head ----
  float msg[28];
  {
    const char* rp = ub + tid * kRowB;
#pragma unroll
    for (int c = 0; c < 7; ++c) {
      const f32x4 v = *(const f32x4*)(rp + c * 16);
      msg[c * 4 + 0] = v[0];
      msg[c * 4 + 1] = v[1];
      msg[c * 4 + 2] = v[2];
      msg[c * 4 + 3] = v[3];
    }
  }
#pragma unroll
  for (int d = 1; d < 64; d <<= 1) {
    const int od = __shfl_down(dstv, d);
    const bool same = (lane + d < 64) && (od == dstv);
#pragma unroll
    for (int j = 0; j < 28; j++) {
      const float ov = __shfl_down(msg[j], d);
      if (same) msg[j] += ov;
    }
  }
  const int pd = __shfl_up(dstv, 1);
  if ((lane == 0 || pd != dstv) && dstv >= 0) {
    float* ap = agg + (size_t)dstv * kAttr;
#pragma unroll
    for (int j = 0; j < 28; j++) atomicAdd(ap + j, msg[j]);
  }
}

// ---------- F: finalize ----------
__global__ __launch_bounds__(256) void tfn_finalize_kernel(
    const float* __restrict__ node_attr, const int* __restrict__ cnt,
    float* __restrict__ out, int total) {
  const int i = blockIdx.x * blockDim.x + threadIdx.x;
  if (i >= total) return;
  const int n = i / kAttr;
  const float c = fmaxf((float)cnt[n], 1.0f);
  out[i] = node_attr[i] + out[i] / c;
}

extern "C" void kernel_launch(void* const* d_in, const int* in_sizes, int n_in,
                              void* d_out, int out_size, void* d_ws, size_t ws_size,
                              hipStream_t stream) {
  const float* node_attr = (const float*)d_in[0];
  const float* pos = (const float*)d_in[1];
  const float* W1 = (const float*)d_in[2];
  const float* b1 = (const float*)d_in[3];
  const float* W2 = (const float*)d_in[4];
  const float* b2 = (const float*)d_in[5];
  const int* edge_index = (const int*)d_in[6];

  const int N = in_sizes[0] / kAttr;
  const int E = in_sizes[6] / 2;

  // ws layout: [img1 12288B][img2 51200B][cnt N][cur N][sedge E int2] ~2.7MB
  // (ws proven >= 7.8MB in r7).
  char* wsc = (char*)d_ws;
  unsigned short* img1 = (unsigned short*)wsc;
  unsigned short* img2 = (unsigned short*)(wsc + kImg1Bytes);
  int* cnt = (int*)(wsc + kImg1Bytes + kImg2Bytes);
  int* cur = cnt + N;
  int2* sedge = (int2*)(cur + N);

  float* agg = (float*)d_out;
  const int aggN4 = out_size / 4;
  const int eblocks = (E + 255) / 256;
  const int total = N * kAttr;

  // 6 dispatches, all plain (r9 lesson: no grid.sync; r8 lesson: no mega-fuse).
  init_kernel<<<512, 256, 0, stream>>>(W1, W2, img1, img2, cnt, agg, aggN4, N);
  hist_kernel<<<eblocks, 256, 0, stream>>>(edge_index, cnt, E);
  scan_kernel<<<1, 256, 0, stream>>>(cnt, cur, N);
  scatter_kernel<<<eblocks, 256, 0, stream>>>(edge_index, cur, sedge, E);
  tfn_mfma_kernel<<<eblocks, 256, 0, stream>>>(
      node_attr, pos, b1, b2, (const char*)img1, (const char*)img2,
      sedge, agg, E);
  tfn_finalize_kernel<<<(total + 255) / 256, 256, 0, stream>>>(
      node_attr, cnt, (float*)d_out, total);
}

// Round 11
// 135.389 us; speedup vs baseline: 4.5028x; 1.0243x over previous
//
#include <hip/hip_runtime.h>
#include <math.h>

typedef _Float16 half8 __attribute__((ext_vector_type(8)));
typedef float f32x4 __attribute__((ext_vector_type(4)));
typedef unsigned int u32x4 __attribute__((ext_vector_type(4)));
typedef unsigned int u32x2 __attribute__((ext_vector_type(2)));

namespace {
constexpr int kNS = 16;
constexpr int kNV = 4;
constexpr int kNG = 50;
constexpr int kHID = 64;
constexpr int kAttr = 28;                 // NS + 3*NV
constexpr int kWNUM = 400;
constexpr float kStep = 5.0f / 49.0f;
constexpr float kCoeff = -0.5f / (kStep * kStep);
constexpr float kSqrt3 = 1.7320508075688772f;
constexpr float kInvSqrt3 = 0.57735026918962576f;
constexpr float kInvSqrt20 = 0.22360679774997896f;
// Row = 208 B (13 granules): 52 words == 20 mod 32 -> 16 rows spread over 8
// bank-offset classes (2 lanes/bank = free). No XOR swizzle (r3 lesson).
constexpr int kRowB = 208;
constexpr int kImg1Bytes = 96 * 64 * 2;   // 12288
constexpr int kImg2Bytes = 64 * 400 * 2;  // 51200
}  // namespace

// f16 end-to-end (r6-r10: absmax 0.06-0.09 vs threshold 0.101; bf16 too thin).
// (_Float16) cast = hardware v_cvt_f16_f32 RNE (r5: hip bf16 helpers truncate).
__device__ __forceinline__ unsigned short f2h(float x) {
  _Float16 h = (_Float16)x;
  unsigned short r;
  __builtin_memcpy(&r, &h, 2);
  return r;
}
__device__ __forceinline__ unsigned pack2(float lo, float hi) {
  return (unsigned)f2h(lo) | ((unsigned)f2h(hi) << 16);
}

// ---------- A: fused init (zero agg + zero cnt + f16 weight images) ----------
// r9 lesson: NO cooperative grid.sync (537us spin at 2048 blocks). Plain
// dispatches provide ordering; r4/r10 proved each aux phase <9us.
__global__ __launch_bounds__(256) void init_kernel(
    const float* __restrict__ W1, const float* __restrict__ W2,
    unsigned short* __restrict__ img1, unsigned short* __restrict__ img2,
    int* __restrict__ cnt, float* __restrict__ agg, int aggN4, int N) {
  const int gtid = blockIdx.x * 256 + threadIdx.x;
  const int gsz = gridDim.x * 256;
  f32x4* agg4 = (f32x4*)agg;
  for (int i = gtid; i < aggN4; i += gsz) agg4[i] = f32x4{0.f, 0.f, 0.f, 0.f};
  for (int i = gtid; i < N; i += gsz) cnt[i] = 0;
  // img layout: element (k, n) at byte ((k>>3)*W + n)*16 + 2*(k&7)
  for (int i = gtid; i < 96 * 64 + 64 * 400; i += gsz) {
    if (i < 96 * 64) {
      const int m = i >> 6, n = i & 63;
      float v = 0.0f;
      if (m < 50) v = W1[m * 64 + n];                        // gaussian rows
      else if (m >= 56 && m < 88) v = W1[(m - 6) * 64 + n];  // ss, ds rows
      img1[((m >> 3) * 64 + n) * 8 + (m & 7)] = f2h(v);
    } else {
      const int j = i - 96 * 64;
      const int m = j / 400, n = j % 400;
      img2[((m >> 3) * 400 + n) * 8 + (m & 7)] = f2h(W2[m * 400 + n]);
    }
  }
}

// ---------- B: histogram of dst ----------
__global__ __launch_bounds__(256) void hist_kernel(
    const int* __restrict__ edge_index, int* __restrict__ cnt, int E) {
  const int e = blockIdx.x * blockDim.x + threadIdx.x;
  if (e >= E) return;
  atomicAdd(cnt + edge_index[E + e], 1);
}

// ---------- C: exclusive scan cnt -> cur (single block; r4-proven) ----------
__global__ __launch_bounds__(256) void scan_kernel(
    const int* __restrict__ cnt, int* __restrict__ cur, int N) {
  __shared__ int sums[256];
  const int tid = threadIdx.x;
  const int chunk = (N + 255) / 256;
  const int base = tid * chunk;
  int s = 0;
  for (int j = 0; j < chunk; j++) {
    const int i = base + j;
    if (i < N) s += cnt[i];
  }
  sums[tid] = s;
  __syncthreads();
  for (int d = 1; d < 256; d <<= 1) {
    const int y = (tid >= d) ? sums[tid - d] : 0;
    __syncthreads();
    sums[tid] += y;
    __syncthreads();
  }
  int run = sums[tid] - s;
  for (int j = 0; j < chunk; j++) {
    const int i = base + j;
    if (i < N) { cur[i] = run; run += cnt[i]; }
  }
}

// ---------- D: scatter into dst-sorted order (fused int2 records) ----------
__global__ __launch_bounds__(256) void scatter_kernel(
    const int* __restrict__ edge_index, int* __restrict__ cur,
    int2* __restrict__ sedge, int E) {
  const int e = blockIdx.x * blockDim.x + threadIdx.x;
  if (e >= E) return;
  const int s = edge_index[e];
  const int d = edge_index[E + e];
  const int p = atomicAdd(cur + d, 1);
  sedge[p] = int2{s, d};
}

// ---------- E: main MFMA edge kernel ----------
// r10->r11: ax[12KB] eliminated — o0[20] now stored as f32 in the DEAD h
// region of each ub row (chunks 0..4, after hf is hoisted to registers).
// LDS 65536 -> 53248 => 3 blocks/CU (was 2): latency-bound kernel gets 50%
// more waves/SIMD. Bonus: o0/ss consumed at f32 (one less f16 rounding).
// Per wave: 64 edges (4 groups of 16). All LDS traffic is wave-local; same-
// wave DS ops retire in program order, so the phase overwrites are safe.
// ub row (208B) timeline: ef(96 f16, chunks 0..11) -> h(chunks 0..7) +
// sh/v1 stash(chunks 8..11) -> o0 f32(chunks 0..4, after hf hoist) ->
// msg(28 f32, chunks 0..6).
__global__ __launch_bounds__(256, 3) void tfn_mfma_kernel(
    const float* __restrict__ node_attr, const float* __restrict__ pos,
    const float* __restrict__ b1, const float* __restrict__ b2,
    const char* __restrict__ img1, const char* __restrict__ img2,
    const int2* __restrict__ sedge, float* __restrict__ agg, int E) {
  __shared__ __align__(16) char ub[256 * kRowB];   // 53248 B (3 blocks/CU)

  const int tid = threadIdx.x;
  const int t = blockIdx.x * 256 + tid;
  const int lane = tid & 63;
  const int wv = tid >> 6;
  const int lc = lane & 15, lq = lane >> 4;

  const bool valid = (t < E);
  int src = 0, dstv = -1;
  if (valid) {
    const int2 se = sedge[t];
    src = se.x;
    dstv = se.y;
  }
  const int dn = valid ? dstv : 0;

  // ---- geometry ----
  const float psx = pos[src * 3 + 0], psy = pos[src * 3 + 1], psz = pos[src * 3 + 2];
  const float pdx = pos[dn * 3 + 0], pdy = pos[dn * 3 + 1], pdz = pos[dn * 3 + 2];
  const float vx = pdx - psx, vy = pdy - psy, vz = pdz - psz;
  const float dist = sqrtf(vx * vx + vy * vy + vz * vz);
  const float rinv = 1.0f / fmaxf(dist, 1e-8f);
  const float sh0 = kSqrt3 * (vy * rinv);
  const float sh1 = kSqrt3 * (vz * rinv);
  const float sh2 = kSqrt3 * (vx * rinv);

  const float* nas = node_attr + (size_t)src * kAttr;
  const float* nad = node_attr + (size_t)dn * kAttr;
  const float4 sa = *(const float4*)(nas + 0);
  const float4 sb = *(const float4*)(nas + 4);
  const float4 sc4 = *(const float4*)(nas + 8);
  const float4 sd4 = *(const float4*)(nas + 12);
  const float4 va = *(const float4*)(nas + 16);
  const float4 vb = *(const float4*)(nas + 20);
  const float4 vc = *(const float4*)(nas + 24);
  const float4 da = *(const float4*)(nad + 0);
  const float4 db = *(const float4*)(nad + 4);
  const float4 dc4 = *(const float4*)(nad + 8);
  const float4 dd4 = *(const float4*)(nad + 12);

  char* myrow = ub + tid * kRowB;

  // ---- write ef row (96 f16): [gauss50 | 0x6 | ss16 | ds16 | 0x8] ----
  {
    const float base = dist + 1e-6f;
#pragma unroll
    for (int c = 0; c < 6; ++c) {
      unsigned p[4];
#pragma unroll
      for (int u = 0; u < 4; ++u) {
        const int k = c * 8 + u * 2;
        const float d0 = base - (float)k * kStep;
        const float d1 = base - (float)(k + 1) * kStep;
        p[u] = pack2(__expf(kCoeff * d0 * d0), __expf(kCoeff * d1 * d1));
      }
      *(u32x4*)(myrow + c * 16) = u32x4{p[0], p[1], p[2], p[3]};
    }
    const float d0 = base - 48.0f * kStep, d1 = base - 49.0f * kStep;
    *(u32x4*)(myrow + 6 * 16) =
        u32x4{pack2(__expf(kCoeff * d0 * d0), __expf(kCoeff * d1 * d1)), 0u, 0u, 0u};
    *(u32x4*)(myrow + 7 * 16) =
        u32x4{pack2(sa.x, sa.y), pack2(sa.z, sa.w), pack2(sb.x, sb.y), pack2(sb.z, sb.w)};
    *(u32x4*)(myrow + 8 * 16) =
        u32x4{pack2(sc4.x, sc4.y), pack2(sc4.z, sc4.w), pack2(sd4.x, sd4.y), pack2(sd4.z, sd4.w)};
    *(u32x4*)(myrow + 9 * 16) =
        u32x4{pack2(da.x, da.y), pack2(da.z, da.w), pack2(db.x, db.y), pack2(db.z, db.w)};
    *(u32x4*)(myrow + 10 * 16) =
        u32x4{pack2(dc4.x, dc4.y), pack2(dc4.z, dc4.w), pack2(dd4.x, dd4.y), pack2(dd4.z, dd4.w)};
    *(u32x4*)(myrow + 11 * 16) = u32x4{0u, 0u, 0u, 0u};
  }

  const float v1f[12] = {va.x, va.y, va.z, va.w, vb.x, vb.y, vb.z, vb.w,
                         vc.x, vc.y, vc.z, vc.w};

  // ---- hoist ef fragments (B-operand: lane holds ef[e=g*16+lc][k=(ks*4+lq)*8+j]) ----
  half8 eff[4][3];
#pragma unroll
  for (int g = 0; g < 4; ++g) {
    const char* rp = ub + (wv * 64 + g * 16 + lc) * kRowB;
#pragma unroll
    for (int ks = 0; ks < 3; ++ks)
      eff[g][ks] = *(const half8*)(rp + (ks * 4 + lq) * 16);
  }

  // ---- stash sh/v1 as f32 into chunks 8..11 (ef chunks 8..11 now dead) ----
  *(f32x4*)(myrow + 8 * 16) = f32x4{sh0, sh1, sh2, v1f[0]};
  *(f32x4*)(myrow + 9 * 16) = f32x4{v1f[1], v1f[2], v1f[3], v1f[4]};
  *(f32x4*)(myrow + 10 * 16) = f32x4{v1f[5], v1f[6], v1f[7], v1f[8]};
  *(f32x4*)(myrow + 11 * 16) = f32x4{v1f[9], v1f[10], v1f[11], 0.0f};

  // ---- MFMA-1: h[n][e] = relu(b1[n] + sum_k W1p[k][n] ef[e][k]) ----
#pragma unroll
  for (int nt = 0; nt < 4; ++nt) {
    const half8 a0 = *(const half8*)(img1 + ((0 + lq) * 64 + nt * 16 + lc) * 16);
    const half8 a1 = *(const half8*)(img1 + ((4 + lq) * 64 + nt * 16 + lc) * 16);
    const half8 a2 = *(const half8*)(img1 + ((8 + lq) * 64 + nt * 16 + lc) * 16);
    const f32x4 bias = *(const f32x4*)(b1 + nt * 16 + lq * 4);
#pragma unroll
    for (int g = 0; g < 4; ++g) {
      f32x4 acc = bias;
      acc = __builtin_amdgcn_mfma_f32_16x16x32_f16(a0, eff[g][0], acc, 0, 0, 0);
      acc = __builtin_amdgcn_mfma_f32_16x16x32_f16(a1, eff[g][1], acc, 0, 0, 0);
      acc = __builtin_amdgcn_mfma_f32_16x16x32_f16(a2, eff[g][2], acc, 0, 0, 0);
      const unsigned p0 = pack2(fmaxf(acc[0], 0.0f), fmaxf(acc[1], 0.0f));
      const unsigned p1 = pack2(fmaxf(acc[2], 0.0f), fmaxf(acc[3], 0.0f));
      const int row = wv * 64 + g * 16 + lc;
      // n = nt*16 + lq*4 + r -> byte 2n = nt*32 + lq*8
      *(u32x2*)(ub + row * kRowB + nt * 32 + lq * 8) = u32x2{p0, p1};
    }
  }

  // ---- load h fragments (B-operand: lane holds h[k][e=g*16+lc]) ----
  half8 hf[4][2];
#pragma unroll
  for (int g = 0; g < 4; ++g) {
    const char* rp = ub + (wv * 64 + g * 16 + lc) * kRowB;
    hf[g][0] = *(const half8*)(rp + (0 + lq) * 16);
    hf[g][1] = *(const half8*)(rp + (4 + lq) * 16);
  }

  // ---- hoist per-edge sh / v1 (lane owns edge lc of each group) ----
  float shv[4][3], v1h[4][3];
#pragma unroll
  for (int g = 0; g < 4; ++g) {
    const char* rp = ub + (wv * 64 + g * 16 + lc) * kRowB;
#pragma unroll
    for (int c = 0; c < 3; ++c) {
      shv[g][c] = *(const float*)(rp + 128 + 4 * c);
      v1h[g][c] = *(const float*)(rp + 140 + 12 * lq + 4 * c);
    }
  }

  // ---- o0[20] as f32 into chunks 0..4 (h region dead now that hf is in regs) ----
  {
    const float t0 = (v1f[0] * sh0 + v1f[1] * sh1 + v1f[2] * sh2) * kInvSqrt3;
    const float t1 = (v1f[3] * sh0 + v1f[4] * sh1 + v1f[5] * sh2) * kInvSqrt3;
    const float t2 = (v1f[6] * sh0 + v1f[7] * sh1 + v1f[8] * sh2) * kInvSqrt3;
    const float t3 = (v1f[9] * sh0 + v1f[10] * sh1 + v1f[11] * sh2) * kInvSqrt3;
    *(f32x4*)(myrow + 0) = f32x4{sa.x, sa.y, sa.z, sa.w};
    *(f32x4*)(myrow + 16) = f32x4{sb.x, sb.y, sb.z, sb.w};
    *(f32x4*)(myrow + 32) = f32x4{sc4.x, sc4.y, sc4.z, sc4.w};
    *(f32x4*)(myrow + 48) = f32x4{sd4.x, sd4.y, sd4.z, sd4.w};
    *(f32x4*)(myrow + 64) = f32x4{t0, t1, t2, t3};
  }

  // ---- MFMA-2 + fused contraction. D[n][e]: lane owns edge lc, n = 16nt+4lq+r ----
  float macc0[4][4] = {};
  float macc1[4][4][3] = {};

#pragma unroll 5
  for (int nt = 0; nt < 20; ++nt) {
    const half8 w0 = *(const half8*)(img2 + ((0 + lq) * 400 + nt * 16 + lc) * 16);
    const half8 w1 = *(const half8*)(img2 + ((4 + lq) * 400 + nt * 16 + lc) * 16);
    const f32x4 bias = *(const f32x4*)(b2 + nt * 16 + lq * 4);
#pragma unroll
    for (int g = 0; g < 4; ++g) {
      f32x4 acc = bias;
      acc = __builtin_amdgcn_mfma_f32_16x16x32_f16(w0, hf[g][0], acc, 0, 0, 0);
      acc = __builtin_amdgcn_mfma_f32_16x16x32_f16(w1, hf[g][1], acc, 0, 0, 0);
      const char* rp0 = ub + (wv * 64 + g * 16 + lc) * kRowB;
      const float o0v = *(const float*)(rp0 + 4 * nt);   // broadcast (4 lanes/addr)
#pragma unroll
      for (int r = 0; r < 4; ++r) macc0[g][r] = fmaf(o0v, acc[r], macc0[g][r]);
    }
  }
#pragma unroll
  for (int nt = 20; nt < 24; ++nt) {
    const half8 w0 = *(const half8*)(img2 + ((0 + lq) * 400 + nt * 16 + lc) * 16);
    const half8 w1 = *(const half8*)(img2 + ((4 + lq) * 400 + nt * 16 + lc) * 16);
    const f32x4 bias = *(const f32x4*)(b2 + nt * 16 + lq * 4);
#pragma unroll
    for (int g = 0; g < 4; ++g) {
      f32x4 acc = bias;
      acc = __builtin_amdgcn_mfma_f32_16x16x32_f16(w0, hf[g][0], acc, 0, 0, 0);
      acc = __builtin_amdgcn_mfma_f32_16x16x32_f16(w1, hf[g][1], acc, 0, 0, 0);
      const char* rp0 = ub + (wv * 64 + g * 16 + lc) * kRowB;
      // i = 4*(nt-20) + lq, o = r; o1[i] = ss[i] * sh; ss[i] = o0[i] (f32)
      const float ssv = *(const float*)(rp0 + 16 * (nt - 20) + 4 * lq);
      float pc[3];
#pragma unroll
      for (int c = 0; c < 3; ++c) pc[c] = ssv * shv[g][c];
#pragma unroll
      for (int r = 0; r < 4; ++r)
#pragma unroll
        for (int c = 0; c < 3; ++c)
          macc1[g][r][c] = fmaf(pc[c], acc[r], macc1[g][r][c]);
    }
  }
  {  // nt = 24: i = 16 + lq, o1 row = in_1o
    const int nt = 24;
    const half8 w0 = *(const half8*)(img2 + ((0 + lq) * 400 + nt * 16 + lc) * 16);
    const half8 w1 = *(const half8*)(img2 + ((4 + lq) * 400 + nt * 16 + lc) * 16);
    const f32x4 bias = *(const f32x4*)(b2 + nt * 16 + lq * 4);
#pragma unroll
    for (int g = 0; g < 4; ++g) {
      f32x4 acc = bias;
      acc = __builtin_amdgcn_mfma_f32_16x16x32_f16(w0, hf[g][0], acc, 0, 0, 0);
      acc = __builtin_amdgcn_mfma_f32_16x16x32_f16(w1, hf[g][1], acc, 0, 0, 0);
#pragma unroll
      for (int r = 0; r < 4; ++r)
#pragma unroll
        for (int c = 0; c < 3; ++c)
          macc1[g][r][c] = fmaf(v1h[g][c], acc[r], macc1[g][r][c]);
    }
  }

  // ---- finish msg1 (reduce i-partition across lq groups), scale, write msg rows ----
#pragma unroll
  for (int g = 0; g < 4; ++g)
#pragma unroll
    for (int r = 0; r < 4; ++r)
#pragma unroll
      for (int c = 0; c < 3; ++c) {
        float x = macc1[g][r][c];
        x += __shfl_xor(x, 16);
        x += __shfl_xor(x, 32);
        macc1[g][r][c] = x * kInvSqrt20;
      }
#pragma unroll
  for (int g = 0; g < 4; ++g) {
    char* rp = ub + (wv * 64 + g * 16 + lc) * kRowB;
    *(f32x4*)(rp + lq * 16) =
        f32x4{macc0[g][0] * kInvSqrt20, macc0[g][1] * kInvSqrt20,
              macc0[g][2] * kInvSqrt20, macc0[g][3] * kInvSqrt20};
    f32x4 m1;
    if (lq == 1)
      m1 = f32x4{macc1[g][0][0], macc1[g][0][1], macc1[g][0][2], macc1[g][1][0]};
    else if (lq == 2)
      m1 = f32x4{macc1[g][1][1], macc1[g][1][2], macc1[g][2][0], macc1[g][2][1]};
    else
      m1 = f32x4{macc1[g][2][2], macc1[g][3][0], macc1[g][3][1], macc1[g][3][2]};
    if (lq != 0) *(f32x4*)(rp + 48 + lq * 16) = m1;
  }

  // ---- read back own msg, segmented wave reduction, one atomic per segment head ----
  float msg[28];
  {
    const char* rp = ub + tid * kRowB;
#pragma unroll
    for (int c = 0; c < 7; ++c) {
      const f32x4 v = *(const f32x4*)(rp + c * 16);
      msg[c * 4 + 0] = v[0];
      msg[c * 4 + 1] = v[1];
      msg[c * 4 + 2] = v[2];
      msg[c * 4 + 3] = v[3];
    }
  }
#pragma unroll
  for (int d = 1; d < 64; d <<= 1) {
    const int od = __shfl_down(dstv, d);
    const bool same = (lane + d < 64) && (od == dstv);
#pragma unroll
    for (int j = 0; j < 28; j++) {
      const float ov = __shfl_down(msg[j], d);
      if (same) msg[j] += ov;
    }
  }
  const int pd = __shfl_up(dstv, 1);
  if ((lane == 0 || pd != dstv) && dstv >= 0) {
    float* ap = agg + (size_t)dstv * kAttr;
#pragma unroll
    for (int j = 0; j < 28; j++) atomicAdd(ap + j, msg[j]);
  }
}

// ---------- F: finalize ----------
__global__ __launch_bounds__(256) void tfn_finalize_kernel(
    const float* __restrict__ node_attr, const int* __restrict__ cnt,
    float* __restrict__ out, int total) {
  const int i = blockIdx.x * blockDim.x + threadIdx.x;
  if (i >= total) return;
  const int n = i / kAttr;
  const float c = fmaxf((float)cnt[n], 1.0f);
  out[i] = node_attr[i] + out[i] / c;
}

extern "C" void kernel_launch(void* const* d_in, const int* in_sizes, int n_in,
                              void* d_out, int out_size, void* d_ws, size_t ws_size,
                              hipStream_t stream) {
  const float* node_attr = (const float*)d_in[0];
  const float* pos = (const float*)d_in[1];
  const float* W1 = (const float*)d_in[2];
  const float* b1 = (const float*)d_in[3];
  const float* W2 = (const float*)d_in[4];
  const float* b2 = (const float*)d_in[5];
  const int* edge_index = (const int*)d_in[6];

  const int N = in_sizes[0] / kAttr;
  const int E = in_sizes[6] / 2;

  // ws layout: [img1 12288B][img2 51200B][cnt N][cur N][sedge E int2] ~2.7MB
  char* wsc = (char*)d_ws;
  unsigned short* img1 = (unsigned short*)wsc;
  unsigned short* img2 = (unsigned short*)(wsc + kImg1Bytes);
  int* cnt = (int*)(wsc + kImg1Bytes + kImg2Bytes);
  int* cur = cnt + N;
  int2* sedge = (int2*)(cur + N);

  float* agg = (float*)d_out;
  const int aggN4 = out_size / 4;
  const int eblocks = (E + 255) / 256;
  const int total = N * kAttr;

  // 6 dispatches, all plain (r9: no grid.sync; r8: no mega-fuse).
  init_kernel<<<512, 256, 0, stream>>>(W1, W2, img1, img2, cnt, agg, aggN4, N);
  hist_kernel<<<eblocks, 256, 0, stream>>>(edge_index, cnt, E);
  scan_kernel<<<1, 256, 0, stream>>>(cnt, cur, N);
  scatter_kernel<<<eblocks, 256, 0, stream>>>(edge_index, cur, sedge, E);
  tfn_mfma_kernel<<<eblocks, 256, 0, stream>>>(
      node_attr, pos, b1, b2, (const char*)img1, (const char*)img2,
      sedge, agg, E);
  tfn_finalize_kernel<<<(total + 255) / 256, 256, 0, stream>>>(
      node_attr, cnt, (float*)d_out, total);
}

// Round 12
// 134.646 us; speedup vs baseline: 4.5276x; 1.0055x over previous
//
#include <hip/hip_runtime.h>
#include <math.h>

typedef _Float16 half8 __attribute__((ext_vector_type(8)));
typedef float f32x4 __attribute__((ext_vector_type(4)));
typedef unsigned int u32x4 __attribute__((ext_vector_type(4)));
typedef unsigned int u32x2 __attribute__((ext_vector_type(2)));

namespace {
constexpr int kNS = 16;
constexpr int kNV = 4;
constexpr int kNG = 50;
constexpr int kHID = 64;
constexpr int kAttr = 28;                 // NS + 3*NV
constexpr int kWNUM = 400;
constexpr float kStep = 5.0f / 49.0f;
constexpr float kCoeff = -0.5f / (kStep * kStep);
constexpr float kSqrt3 = 1.7320508075688772f;
constexpr float kInvSqrt3 = 0.57735026918962576f;
constexpr float kInvSqrt20 = 0.22360679774997896f;
// Row = 208 B (13 granules): 52 words == 20 mod 32 -> 16 rows spread over 8
// bank-offset classes (2 lanes/bank = free). No XOR swizzle (r3 lesson).
constexpr int kRowB = 208;
constexpr int kImg1Bytes = 96 * 64 * 2;   // 12288
constexpr int kImg2Bytes = 64 * 400 * 2;  // 51200
}  // namespace

// f16 end-to-end (r6-r11: absmax 0.016-0.09 vs threshold 0.101; bf16 too thin).
// (_Float16) cast = hardware v_cvt_f16_f32 RNE (r5: hip bf16 helpers truncate).
__device__ __forceinline__ unsigned short f2h(float x) {
  _Float16 h = (_Float16)x;
  unsigned short r;
  __builtin_memcpy(&r, &h, 2);
  return r;
}
__device__ __forceinline__ unsigned pack2(float lo, float hi) {
  return (unsigned)f2h(lo) | ((unsigned)f2h(hi) << 16);
}

// ---------- A: fused init (agg = node_attr + zero cnt + f16 weight images) ----
// r12: agg is seeded with node_attr (copy, not zero) and the main kernel
// atomically adds PRE-NORMALIZED messages (scaled by 1/cnt) -> the finalize
// dispatch is gone entirely (6 -> 5 dispatches, ~10us of gap+launch saved).
// r9 lesson: NO cooperative grid.sync. Plain dispatches provide ordering.
__global__ __launch_bounds__(256) void init_kernel(
    const float* __restrict__ W1, const float* __restrict__ W2,
    const float* __restrict__ node_attr,
    unsigned short* __restrict__ img1, unsigned short* __restrict__ img2,
    int* __restrict__ cnt, float* __restrict__ agg, int aggN4, int N) {
  const int gtid = blockIdx.x * 256 + threadIdx.x;
  const int gsz = gridDim.x * 256;
  f32x4* agg4 = (f32x4*)agg;
  const f32x4* na4 = (const f32x4*)node_attr;
  for (int i = gtid; i < aggN4; i += gsz) agg4[i] = na4[i];
  for (int i = gtid; i < N; i += gsz) cnt[i] = 0;
  // img layout: element (k, n) at byte ((k>>3)*W + n)*16 + 2*(k&7)
  for (int i = gtid; i < 96 * 64 + 64 * 400; i += gsz) {
    if (i < 96 * 64) {
      const int m = i >> 6, n = i & 63;
      float v = 0.0f;
      if (m < 50) v = W1[m * 64 + n];                        // gaussian rows
      else if (m >= 56 && m < 88) v = W1[(m - 6) * 64 + n];  // ss, ds rows
      img1[((m >> 3) * 64 + n) * 8 + (m & 7)] = f2h(v);
    } else {
      const int j = i - 96 * 64;
      const int m = j / 400, n = j % 400;
      img2[((m >> 3) * 400 + n) * 8 + (m & 7)] = f2h(W2[m * 400 + n]);
    }
  }
}

// ---------- B: histogram of dst ----------
__global__ __launch_bounds__(256) void hist_kernel(
    const int* __restrict__ edge_index, int* __restrict__ cnt, int E) {
  const int e = blockIdx.x * blockDim.x + threadIdx.x;
  if (e >= E) return;
  atomicAdd(cnt + edge_index[E + e], 1);
}

// ---------- C: exclusive scan cnt -> cur (single block; r4-proven) ----------
__global__ __launch_bounds__(256) void scan_kernel(
    const int* __restrict__ cnt, int* __restrict__ cur, int N) {
  __shared__ int sums[256];
  const int tid = threadIdx.x;
  const int chunk = (N + 255) / 256;
  const int base = tid * chunk;
  int s = 0;
  for (int j = 0; j < chunk; j++) {
    const int i = base + j;
    if (i < N) s += cnt[i];
  }
  sums[tid] = s;
  __syncthreads();
  for (int d = 1; d < 256; d <<= 1) {
    const int y = (tid >= d) ? sums[tid - d] : 0;
    __syncthreads();
    sums[tid] += y;
    __syncthreads();
  }
  int run = sums[tid] - s;
  for (int j = 0; j < chunk; j++) {
    const int i = base + j;
    if (i < N) { cur[i] = run; run += cnt[i]; }
  }
}

// ---------- D: scatter into dst-sorted order (fused int2 records) ----------
__global__ __launch_bounds__(256) void scatter_kernel(
    const int* __restrict__ edge_index, int* __restrict__ cur,
    int2* __restrict__ sedge, int E) {
  const int e = blockIdx.x * blockDim.x + threadIdx.x;
  if (e >= E) return;
  const int s = edge_index[e];
  const int d = edge_index[E + e];
  const int p = atomicAdd(cur + d, 1);
  sedge[p] = int2{s, d};
}

// ---------- E: main MFMA edge kernel ----------
// Per wave: 64 edges (4 groups of 16). All LDS traffic is wave-local; same-
// wave DS ops retire in program order, so the phase overwrites are safe.
// ub row (208B) timeline: ef(96 f16, chunks 0..11) -> h(chunks 0..7) +
// sh/v1 stash(chunks 8..11) -> o0 f32(chunks 0..4, after hf hoist) ->
// msg(28 f32, chunks 0..6). LDS 53248 B => 3 blocks/CU.
// r12: segment heads scale msg by 1/max(cnt[dst],1) before atomicAdd
// (pre-normalized aggregation; agg pre-seeded with node_attr by init).
__global__ __launch_bounds__(256, 3) void tfn_mfma_kernel(
    const float* __restrict__ node_attr, const float* __restrict__ pos,
    const float* __restrict__ b1, const float* __restrict__ b2,
    const char* __restrict__ img1, const char* __restrict__ img2,
    const int2* __restrict__ sedge, const int* __restrict__ cnt,
    float* __restrict__ agg, int E) {
  __shared__ __align__(16) char ub[256 * kRowB];   // 53248 B (3 blocks/CU)

  const int tid = threadIdx.x;
  const int t = blockIdx.x * 256 + tid;
  const int lane = tid & 63;
  const int wv = tid >> 6;
  const int lc = lane & 15, lq = lane >> 4;

  const bool valid = (t < E);
  int src = 0, dstv = -1;
  if (valid) {
    const int2 se = sedge[t];
    src = se.x;
    dstv = se.y;
  }
  const int dn = valid ? dstv : 0;

  // ---- geometry ----
  const float psx = pos[src * 3 + 0], psy = pos[src * 3 + 1], psz = pos[src * 3 + 2];
  const float pdx = pos[dn * 3 + 0], pdy = pos[dn * 3 + 1], pdz = pos[dn * 3 + 2];
  const float vx = pdx - psx, vy = pdy - psy, vz = pdz - psz;
  const float dist = sqrtf(vx * vx + vy * vy + vz * vz);
  const float rinv = 1.0f / fmaxf(dist, 1e-8f);
  const float sh0 = kSqrt3 * (vy * rinv);
  const float sh1 = kSqrt3 * (vz * rinv);
  const float sh2 = kSqrt3 * (vx * rinv);

  const float* nas = node_attr + (size_t)src * kAttr;
  const float* nad = node_attr + (size_t)dn * kAttr;
  const float4 sa = *(const float4*)(nas + 0);
  const float4 sb = *(const float4*)(nas + 4);
  const float4 sc4 = *(const float4*)(nas + 8);
  const float4 sd4 = *(const float4*)(nas + 12);
  const float4 va = *(const float4*)(nas + 16);
  const float4 vb = *(const float4*)(nas + 20);
  const float4 vc = *(const float4*)(nas + 24);
  const float4 da = *(const float4*)(nad + 0);
  const float4 db = *(const float4*)(nad + 4);
  const float4 dc4 = *(const float4*)(nad + 8);
  const float4 dd4 = *(const float4*)(nad + 12);

  char* myrow = ub + tid * kRowB;

  // ---- write ef row (96 f16): [gauss50 | 0x6 | ss16 | ds16 | 0x8] ----
  {
    const float base = dist + 1e-6f;
#pragma unroll
    for (int c = 0; c < 6; ++c) {
      unsigned p[4];
#pragma unroll
      for (int u = 0; u < 4; ++u) {
        const int k = c * 8 + u * 2;
        const float d0 = base - (float)k * kStep;
        const float d1 = base - (float)(k + 1) * kStep;
        p[u] = pack2(__expf(kCoeff * d0 * d0), __expf(kCoeff * d1 * d1));
      }
      *(u32x4*)(myrow + c * 16) = u32x4{p[0], p[1], p[2], p[3]};
    }
    const float d0 = base - 48.0f * kStep, d1 = base - 49.0f * kStep;
    *(u32x4*)(myrow + 6 * 16) =
        u32x4{pack2(__expf(kCoeff * d0 * d0), __expf(kCoeff * d1 * d1)), 0u, 0u, 0u};
    *(u32x4*)(myrow + 7 * 16) =
        u32x4{pack2(sa.x, sa.y), pack2(sa.z, sa.w), pack2(sb.x, sb.y), pack2(sb.z, sb.w)};
    *(u32x4*)(myrow + 8 * 16) =
        u32x4{pack2(sc4.x, sc4.y), pack2(sc4.z, sc4.w), pack2(sd4.x, sd4.y), pack2(sd4.z, sd4.w)};
    *(u32x4*)(myrow + 9 * 16) =
        u32x4{pack2(da.x, da.y), pack2(da.z, da.w), pack2(db.x, db.y), pack2(db.z, db.w)};
    *(u32x4*)(myrow + 10 * 16) =
        u32x4{pack2(dc4.x, dc4.y), pack2(dc4.z, dc4.w), pack2(dd4.x, dd4.y), pack2(dd4.z, dd4.w)};
    *(u32x4*)(myrow + 11 * 16) = u32x4{0u, 0u, 0u, 0u};
  }

  const float v1f[12] = {va.x, va.y, va.z, va.w, vb.x, vb.y, vb.z, vb.w,
                         vc.x, vc.y, vc.z, vc.w};

  // ---- hoist ef fragments (B-operand: lane holds ef[e=g*16+lc][k=(ks*4+lq)*8+j]) ----
  half8 eff[4][3];
#pragma unroll
  for (int g = 0; g < 4; ++g) {
    const char* rp = ub + (wv * 64 + g * 16 + lc) * kRowB;
#pragma unroll
    for (int ks = 0; ks < 3; ++ks)
      eff[g][ks] = *(const half8*)(rp + (ks * 4 + lq) * 16);
  }

  // ---- stash sh/v1 as f32 into chunks 8..11 (ef chunks 8..11 now dead) ----
  *(f32x4*)(myrow + 8 * 16) = f32x4{sh0, sh1, sh2, v1f[0]};
  *(f32x4*)(myrow + 9 * 16) = f32x4{v1f[1], v1f[2], v1f[3], v1f[4]};
  *(f32x4*)(myrow + 10 * 16) = f32x4{v1f[5], v1f[6], v1f[7], v1f[8]};
  *(f32x4*)(myrow + 11 * 16) = f32x4{v1f[9], v1f[10], v1f[11], 0.0f};

  // ---- MFMA-1: h[n][e] = relu(b1[n] + sum_k W1p[k][n] ef[e][k]) ----
#pragma unroll
  for (int nt = 0; nt < 4; ++nt) {
    const half8 a0 = *(const half8*)(img1 + ((0 + lq) * 64 + nt * 16 + lc) * 16);
    const half8 a1 = *(const half8*)(img1 + ((4 + lq) * 64 + nt * 16 + lc) * 16);
    const half8 a2 = *(const half8*)(img1 + ((8 + lq) * 64 + nt * 16 + lc) * 16);
    const f32x4 bias = *(const f32x4*)(b1 + nt * 16 + lq * 4);
#pragma unroll
    for (int g = 0; g < 4; ++g) {
      f32x4 acc = bias;
      acc = __builtin_amdgcn_mfma_f32_16x16x32_f16(a0, eff[g][0], acc, 0, 0, 0);
      acc = __builtin_amdgcn_mfma_f32_16x16x32_f16(a1, eff[g][1], acc, 0, 0, 0);
      acc = __builtin_amdgcn_mfma_f32_16x16x32_f16(a2, eff[g][2], acc, 0, 0, 0);
      const unsigned p0 = pack2(fmaxf(acc[0], 0.0f), fmaxf(acc[1], 0.0f));
      const unsigned p1 = pack2(fmaxf(acc[2], 0.0f), fmaxf(acc[3], 0.0f));
      const int row = wv * 64 + g * 16 + lc;
      // n = nt*16 + lq*4 + r -> byte 2n = nt*32 + lq*8
      *(u32x2*)(ub + row * kRowB + nt * 32 + lq * 8) = u32x2{p0, p1};
    }
  }

  // ---- load h fragments (B-operand: lane holds h[k][e=g*16+lc]) ----
  half8 hf[4][2];
#pragma unroll
  for (int g = 0; g < 4; ++g) {
    const char* rp = ub + (wv * 64 + g * 16 + lc) * kRowB;
    hf[g][0] = *(const half8*)(rp + (0 + lq) * 16);
    hf[g][1] = *(const half8*)(rp + (4 + lq) * 16);
  }

  // ---- hoist per-edge sh / v1 (lane owns edge lc of each group) ----
  float shv[4][3], v1h[4][3];
#pragma unroll
  for (int g = 0; g < 4; ++g) {
    const char* rp = ub + (wv * 64 + g * 16 + lc) * kRowB;
#pragma unroll
    for (int c = 0; c < 3; ++c) {
      shv[g][c] = *(const float*)(rp + 128 + 4 * c);
      v1h[g][c] = *(const float*)(rp + 140 + 12 * lq + 4 * c);
    }
  }

  // ---- o0[20] as f32 into chunks 0..4 (h region dead now that hf is in regs) ----
  {
    const float t0 = (v1f[0] * sh0 + v1f[1] * sh1 + v1f[2] * sh2) * kInvSqrt3;
    const float t1 = (v1f[3] * sh0 + v1f[4] * sh1 + v1f[5] * sh2) * kInvSqrt3;
    const float t2 = (v1f[6] * sh0 + v1f[7] * sh1 + v1f[8] * sh2) * kInvSqrt3;
    const float t3 = (v1f[9] * sh0 + v1f[10] * sh1 + v1f[11] * sh2) * kInvSqrt3;
    *(f32x4*)(myrow + 0) = f32x4{sa.x, sa.y, sa.z, sa.w};
    *(f32x4*)(myrow + 16) = f32x4{sb.x, sb.y, sb.z, sb.w};
    *(f32x4*)(myrow + 32) = f32x4{sc4.x, sc4.y, sc4.z, sc4.w};
    *(f32x4*)(myrow + 48) = f32x4{sd4.x, sd4.y, sd4.z, sd4.w};
    *(f32x4*)(myrow + 64) = f32x4{t0, t1, t2, t3};
  }

  // ---- MFMA-2 + fused contraction. D[n][e]: lane owns edge lc, n = 16nt+4lq+r ----
  float macc0[4][4] = {};
  float macc1[4][4][3] = {};

#pragma unroll 5
  for (int nt = 0; nt < 20; ++nt) {
    const half8 w0 = *(const half8*)(img2 + ((0 + lq) * 400 + nt * 16 + lc) * 16);
    const half8 w1 = *(const half8*)(img2 + ((4 + lq) * 400 + nt * 16 + lc) * 16);
    const f32x4 bias = *(const f32x4*)(b2 + nt * 16 + lq * 4);
#pragma unroll
    for (int g = 0; g < 4; ++g) {
      f32x4 acc = bias;
      acc = __builtin_amdgcn_mfma_f32_16x16x32_f16(w0, hf[g][0], acc, 0, 0, 0);
      acc = __builtin_amdgcn_mfma_f32_16x16x32_f16(w1, hf[g][1], acc, 0, 0, 0);
      const char* rp0 = ub + (wv * 64 + g * 16 + lc) * kRowB;
      const float o0v = *(const float*)(rp0 + 4 * nt);   // broadcast (4 lanes/addr)
#pragma unroll
      for (int r = 0; r < 4; ++r) macc0[g][r] = fmaf(o0v, acc[r], macc0[g][r]);
    }
  }
#pragma unroll
  for (int nt = 20; nt < 24; ++nt) {
    const half8 w0 = *(const half8*)(img2 + ((0 + lq) * 400 + nt * 16 + lc) * 16);
    const half8 w1 = *(const half8*)(img2 + ((4 + lq) * 400 + nt * 16 + lc) * 16);
    const f32x4 bias = *(const f32x4*)(b2 + nt * 16 + lq * 4);
#pragma unroll
    for (int g = 0; g < 4; ++g) {
      f32x4 acc = bias;
      acc = __builtin_amdgcn_mfma_f32_16x16x32_f16(w0, hf[g][0], acc, 0, 0, 0);
      acc = __builtin_amdgcn_mfma_f32_16x16x32_f16(w1, hf[g][1], acc, 0, 0, 0);
      const char* rp0 = ub + (wv * 64 + g * 16 + lc) * kRowB;
      // i = 4*(nt-20) + lq, o = r; o1[i] = ss[i] * sh; ss[i] = o0[i] (f32)
      const float ssv = *(const float*)(rp0 + 16 * (nt - 20) + 4 * lq);
      float pc[3];
#pragma unroll
      for (int c = 0; c < 3; ++c) pc[c] = ssv * shv[g][c];
#pragma unroll
      for (int r = 0; r < 4; ++r)
#pragma unroll
        for (int c = 0; c < 3; ++c)
          macc1[g][r][c] = fmaf(pc[c], acc[r], macc1[g][r][c]);
    }
  }
  {  // nt = 24: i = 16 + lq, o1 row = in_1o
    const int nt = 24;
    const half8 w0 = *(const half8*)(img2 + ((0 + lq) * 400 + nt * 16 + lc) * 16);
    const half8 w1 = *(const half8*)(img2 + ((4 + lq) * 400 + nt * 16 + lc) * 16);
    const f32x4 bias = *(const f32x4*)(b2 + nt * 16 + lq * 4);
#pragma unroll
    for (int g = 0; g < 4; ++g) {
      f32x4 acc = bias;
      acc = __builtin_amdgcn_mfma_f32_16x16x32_f16(w0, hf[g][0], acc, 0, 0, 0);
      acc = __builtin_amdgcn_mfma_f32_16x16x32_f16(w1, hf[g][1], acc, 0, 0, 0);
#pragma unroll
      for (int r = 0; r < 4; ++r)
#pragma unroll
        for (int c = 0; c < 3; ++c)
          macc1[g][r][c] = fmaf(v1h[g][c], acc[r], macc1[g][r][c]);
    }
  }

  // ---- finish msg1 (reduce i-partition across lq groups), scale, write msg rows ----
#pragma unroll
  for (int g = 0; g < 4; ++g)
#pragma unroll
    for (int r = 0; r < 4; ++r)
#pragma unroll
      for (int c = 0; c < 3; ++c) {
        float x = macc1[g][r][c];
        x += __shfl_xor(x, 16);
        x += __shfl_xor(x, 32);
        macc1[g][r][c] = x * kInvSqrt20;
      }
#pragma unroll
  for (int g = 0; g < 4; ++g) {
    char* rp = ub + (wv * 64 + g * 16 + lc) * kRowB;
    *(f32x4*)(rp + lq * 16) =
        f32x4{macc0[g][0] * kInvSqrt20, macc0[g][1] * kInvSqrt20,
              macc0[g][2] * kInvSqrt20, macc0[g][3] * kInvSqrt20};
    f32x4 m1;
    if (lq == 1)
      m1 = f32x4{macc1[g][0][0], macc1[g][0][1], macc1[g][0][2], macc1[g][1][0]};
    else if (lq == 2)
      m1 = f32x4{macc1[g][1][1], macc1[g][1][2], macc1[g][2][0], macc1[g][2][1]};
    else
      m1 = f32x4{macc1[g][2][2], macc1[g][3][0], macc1[g][3][1], macc1[g][3][2]};
    if (lq != 0) *(f32x4*)(rp + 48 + lq * 16) = m1;
  }

  // ---- read back own msg, segmented wave reduction, one atomic per segment head ----
  float msg[28];
  {
    const char* rp = ub + tid * kRowB;
#pragma unroll
    for (int c = 0; c < 7; ++c) {
      const f32x4 v = *(const f32x4*)(rp + c * 16);
      msg[c * 4 + 0] = v[0];
      msg[c * 4 + 1] = v[1];
      msg[c * 4 + 2] = v[2];
      msg[c * 4 + 3] = v[3];
    }
  }
#pragma unroll
  for (int d = 1; d < 64; d <<= 1) {
    const int od = __shfl_down(dstv, d);
    const bool same = (lane + d < 64) && (od == dstv);
#pragma unroll
    for (int j = 0; j < 28; j++) {
      const float ov = __shfl_down(msg[j], d);
      if (same) msg[j] += ov;
    }
  }
  const int pd = __shfl_up(dstv, 1);
  if ((lane == 0 || pd != dstv) && dstv >= 0) {
    // pre-normalize: agg was seeded with node_attr; adding msg/cnt completes
    // out = node_attr + (segment-sum)/cnt without a finalize pass.
    const float rc = 1.0f / fmaxf((float)cnt[dstv], 1.0f);
    float* ap = agg + (size_t)dstv * kAttr;
#pragma unroll
    for (int j = 0; j < 28; j++) atomicAdd(ap + j, msg[j] * rc);
  }
}

extern "C" void kernel_launch(void* const* d_in, const int* in_sizes, int n_in,
                              void* d_out, int out_size, void* d_ws, size_t ws_size,
                              hipStream_t stream) {
  const float* node_attr = (const float*)d_in[0];
  const float* pos = (const float*)d_in[1];
  const float* W1 = (const float*)d_in[2];
  const float* b1 = (const float*)d_in[3];
  const float* W2 = (const float*)d_in[4];
  const float* b2 = (const float*)d_in[5];
  const int* edge_index = (const int*)d_in[6];

  const int N = in_sizes[0] / kAttr;
  const int E = in_sizes[6] / 2;

  // ws layout: [img1 12288B][img2 51200B][cnt N][cur N][sedge E int2] ~2.7MB
  char* wsc = (char*)d_ws;
  unsigned short* img1 = (unsigned short*)wsc;
  unsigned short* img2 = (unsigned short*)(wsc + kImg1Bytes);
  int* cnt = (int*)(wsc + kImg1Bytes + kImg2Bytes);
  int* cur = cnt + N;
  int2* sedge = (int2*)(cur + N);

  float* agg = (float*)d_out;
  const int aggN4 = out_size / 4;
  const int eblocks = (E + 255) / 256;

  // 5 dispatches, all plain (r9: no grid.sync; r8: no mega-fuse; r12: no
  // finalize — init seeds agg=node_attr and main adds pre-normalized msgs).
  init_kernel<<<512, 256, 0, stream>>>(W1, W2, node_attr, img1, img2, cnt, agg,
                                       aggN4, N);
  hist_kernel<<<eblocks, 256, 0, stream>>>(edge_index, cnt, E);
  scan_kernel<<<1, 256, 0, stream>>>(cnt, cur, N);
  scatter_kernel<<<eblocks, 256, 0, stream>>>(edge_index, cur, sedge, E);
  tfn_mfma_kernel<<<eblocks, 256, 0, stream>>>(
      node_attr, pos, b1, b2, (const char*)img1, (const char*)img2,
      sedge, cnt, agg, E);
}

// Round 13
// 107.673 us; speedup vs baseline: 5.6618x; 1.2505x over previous
//
#include <hip/hip_runtime.h>
#include <math.h>

typedef _Float16 half8 __attribute__((ext_vector_type(8)));
typedef float f32x4 __attribute__((ext_vector_type(4)));
typedef unsigned int u32x4 __attribute__((ext_vector_type(4)));
typedef unsigned int u32x2 __attribute__((ext_vector_type(2)));

namespace {
constexpr int kNS = 16;
constexpr int kNV = 4;
constexpr int kNG = 50;
constexpr int kHID = 64;
constexpr int kAttr = 28;                 // NS + 3*NV
constexpr int kWNUM = 400;
constexpr float kStep = 5.0f / 49.0f;
constexpr float kCoeff = -0.5f / (kStep * kStep);
constexpr float kSqrt3 = 1.7320508075688772f;
constexpr float kInvSqrt3 = 0.57735026918962576f;
constexpr float kInvSqrt20 = 0.22360679774997896f;
// Row = 208 B (13 granules): 52 words == 20 mod 32 -> 16 rows spread over 8
// bank-offset classes (2 lanes/bank = free). No XOR swizzle (r3 lesson).
constexpr int kRowB = 208;
constexpr int kImg1Bytes = 96 * 64 * 2;   // 12288
constexpr int kImg2Bytes = 64 * 400 * 2;  // 51200
}  // namespace

// f16 end-to-end (r6-r12: absmax 0.016-0.09 vs threshold 0.101).
// (_Float16) cast = hardware v_cvt_f16_f32 RNE (r5: hip bf16 helpers truncate).
__device__ __forceinline__ unsigned short f2h(float x) {
  _Float16 h = (_Float16)x;
  unsigned short r;
  __builtin_memcpy(&r, &h, 2);
  return r;
}
__device__ __forceinline__ unsigned pack2(float lo, float hi) {
  return (unsigned)f2h(lo) | ((unsigned)f2h(hi) << 16);
}

// ---------- A: fused init (agg = node_attr; cnt = 0; f16 weight images) ------
// r12 lesson: graph-replay gaps are ~0; aux KERNEL TIME is the cost. Atomic
// throughput ~13 G/s (r1) => each 320K-atomic pass ~20-25us. This round: only
// ONE atomic pass (hist_rank); scatter is atomic-free via saved ranks.
__global__ __launch_bounds__(256) void init_kernel(
    const float* __restrict__ W1, const float* __restrict__ W2,
    const float* __restrict__ node_attr,
    unsigned short* __restrict__ img1, unsigned short* __restrict__ img2,
    int* __restrict__ cnt, float* __restrict__ agg, int aggN4, int N) {
  const int gtid = blockIdx.x * 256 + threadIdx.x;
  const int gsz = gridDim.x * 256;
  f32x4* agg4 = (f32x4*)agg;
  const f32x4* na4 = (const f32x4*)node_attr;
  for (int i = gtid; i < aggN4; i += gsz) agg4[i] = na4[i];
  for (int i = gtid; i < N; i += gsz) cnt[i] = 0;
  // img layout: element (k, n) at byte ((k>>3)*W + n)*16 + 2*(k&7)
  for (int i = gtid; i < 96 * 64 + 64 * 400; i += gsz) {
    if (i < 96 * 64) {
      const int m = i >> 6, n = i & 63;
      float v = 0.0f;
      if (m < 50) v = W1[m * 64 + n];                        // gaussian rows
      else if (m >= 56 && m < 88) v = W1[(m - 6) * 64 + n];  // ss, ds rows
      img1[((m >> 3) * 64 + n) * 8 + (m & 7)] = f2h(v);
    } else {
      const int j = i - 96 * 64;
      const int m = j / 400, n = j % 400;
      img2[((m >> 3) * 400 + n) * 8 + (m & 7)] = f2h(W2[m * 400 + n]);
    }
  }
}

// ---------- B: histogram of dst + per-edge rank (the ONLY atomic pass) -------
__global__ __launch_bounds__(256) void hist_rank_kernel(
    const int* __restrict__ edge_index, int* __restrict__ cnt,
    int* __restrict__ rank, int E) {
  const int e = blockIdx.x * blockDim.x + threadIdx.x;
  if (e >= E) return;
  rank[e] = atomicAdd(cnt + edge_index[E + e], 1);
}

// ---------- C: exclusive scan cnt -> node_start (single block, wave-scan) ----
// r12 rewrite: coalesced int4 loads + shfl_up wave scan + LDS cross-wave
// (old serial-chunk version was ~10-20us of dependent uncoalesced loops).
__global__ __launch_bounds__(256) void scan_kernel(
    const int* __restrict__ cnt, int* __restrict__ node_start, int N) {
  __shared__ int wsum[4];
  const int tid = threadIdx.x;
  const int lane = tid & 63;
  const int wv = tid >> 6;
  const int n4 = (N + 3) >> 2;
  const int tiles = (n4 + 255) / 256;
  int running = 0;
  for (int k = 0; k < tiles; ++k) {
    const int i4 = k * 256 + tid;
    int4 v = {0, 0, 0, 0};
    const int base = i4 * 4;
    if (i4 < n4) {
      if (base + 3 < N) {
        v = *(const int4*)(cnt + base);
      } else {
        if (base + 0 < N) v.x = cnt[base + 0];
        if (base + 1 < N) v.y = cnt[base + 1];
        if (base + 2 < N) v.z = cnt[base + 2];
      }
    }
    const int e1 = v.x, e2 = v.x + v.y, e3 = e2 + v.z, s4 = e3 + v.w;
    int incl = s4;
#pragma unroll
    for (int d = 1; d < 64; d <<= 1) {
      const int y = __shfl_up(incl, d);
      if (lane >= d) incl += y;
    }
    if (lane == 63) wsum[wv] = incl;
    __syncthreads();
    int wbase = 0;
#pragma unroll
    for (int w = 0; w < 4; ++w) wbase += (w < wv) ? wsum[w] : 0;
    const int block_total = wsum[0] + wsum[1] + wsum[2] + wsum[3];
    const int tbase = running + wbase + (incl - s4);
    if (i4 < n4) {
      if (base + 0 < N) node_start[base + 0] = tbase;
      if (base + 1 < N) node_start[base + 1] = tbase + e1;
      if (base + 2 < N) node_start[base + 2] = tbase + e2;
      if (base + 3 < N) node_start[base + 3] = tbase + e3;
    }
    running += block_total;
    __syncthreads();  // wsum reused next tile
  }
}

// ---------- D: scatter (ATOMIC-FREE: slot = node_start[d] + rank[e]) ---------
__global__ __launch_bounds__(256) void scatter_kernel(
    const int* __restrict__ edge_index, const int* __restrict__ node_start,
    const int* __restrict__ rank, int2* __restrict__ sedge, int E) {
  const int e = blockIdx.x * blockDim.x + threadIdx.x;
  if (e >= E) return;
  const int s = edge_index[e];
  const int d = edge_index[E + e];
  sedge[node_start[d] + rank[e]] = int2{s, d};
}

// ---------- E: main MFMA edge kernel (r12 body, FROZEN) ----------
// Per wave: 64 edges (4 groups of 16). All LDS traffic is wave-local; same-
// wave DS ops retire in program order, so the phase overwrites are safe.
// ub row (208B) timeline: ef(96 f16, chunks 0..11) -> h(chunks 0..7) +
// sh/v1 stash(chunks 8..11) -> o0 f32(chunks 0..4, after hf hoist) ->
// msg(28 f32, chunks 0..6). LDS 53248 B => 3 blocks/CU.
// Segment heads scale msg by 1/max(cnt[dst],1) before atomicAdd
// (pre-normalized aggregation; agg pre-seeded with node_attr by init).
__global__ __launch_bounds__(256, 3) void tfn_mfma_kernel(
    const float* __restrict__ node_attr, const float* __restrict__ pos,
    const float* __restrict__ b1, const float* __restrict__ b2,
    const char* __restrict__ img1, const char* __restrict__ img2,
    const int2* __restrict__ sedge, const int* __restrict__ cnt,
    float* __restrict__ agg, int E) {
  __shared__ __align__(16) char ub[256 * kRowB];   // 53248 B (3 blocks/CU)

  const int tid = threadIdx.x;
  const int t = blockIdx.x * 256 + tid;
  const int lane = tid & 63;
  const int wv = tid >> 6;
  const int lc = lane & 15, lq = lane >> 4;

  const bool valid = (t < E);
  int src = 0, dstv = -1;
  if (valid) {
    const int2 se = sedge[t];
    src = se.x;
    dstv = se.y;
  }
  const int dn = valid ? dstv : 0;

  // ---- geometry ----
  const float psx = pos[src * 3 + 0], psy = pos[src * 3 + 1], psz = pos[src * 3 + 2];
  const float pdx = pos[dn * 3 + 0], pdy = pos[dn * 3 + 1], pdz = pos[dn * 3 + 2];
  const float vx = pdx - psx, vy = pdy - psy, vz = pdz - psz;
  const float dist = sqrtf(vx * vx + vy * vy + vz * vz);
  const float rinv = 1.0f / fmaxf(dist, 1e-8f);
  const float sh0 = kSqrt3 * (vy * rinv);
  const float sh1 = kSqrt3 * (vz * rinv);
  const float sh2 = kSqrt3 * (vx * rinv);

  const float* nas = node_attr + (size_t)src * kAttr;
  const float* nad = node_attr + (size_t)dn * kAttr;
  const float4 sa = *(const float4*)(nas + 0);
  const float4 sb = *(const float4*)(nas + 4);
  const float4 sc4 = *(const float4*)(nas + 8);
  const float4 sd4 = *(const float4*)(nas + 12);
  const float4 va = *(const float4*)(nas + 16);
  const float4 vb = *(const float4*)(nas + 20);
  const float4 vc = *(const float4*)(nas + 24);
  const float4 da = *(const float4*)(nad + 0);
  const float4 db = *(const float4*)(nad + 4);
  const float4 dc4 = *(const float4*)(nad + 8);
  const float4 dd4 = *(const float4*)(nad + 12);

  char* myrow = ub + tid * kRowB;

  // ---- write ef row (96 f16): [gauss50 | 0x6 | ss16 | ds16 | 0x8] ----
  {
    const float base = dist + 1e-6f;
#pragma unroll
    for (int c = 0; c < 6; ++c) {
      unsigned p[4];
#pragma unroll
      for (int u = 0; u < 4; ++u) {
        const int k = c * 8 + u * 2;
        const float d0 = base - (float)k * kStep;
        const float d1 = base - (float)(k + 1) * kStep;
        p[u] = pack2(__expf(kCoeff * d0 * d0), __expf(kCoeff * d1 * d1));
      }
      *(u32x4*)(myrow + c * 16) = u32x4{p[0], p[1], p[2], p[3]};
    }
    const float d0 = base - 48.0f * kStep, d1 = base - 49.0f * kStep;
    *(u32x4*)(myrow + 6 * 16) =
        u32x4{pack2(__expf(kCoeff * d0 * d0), __expf(kCoeff * d1 * d1)), 0u, 0u, 0u};
    *(u32x4*)(myrow + 7 * 16) =
        u32x4{pack2(sa.x, sa.y), pack2(sa.z, sa.w), pack2(sb.x, sb.y), pack2(sb.z, sb.w)};
    *(u32x4*)(myrow + 8 * 16) =
        u32x4{pack2(sc4.x, sc4.y), pack2(sc4.z, sc4.w), pack2(sd4.x, sd4.y), pack2(sd4.z, sd4.w)};
    *(u32x4*)(myrow + 9 * 16) =
        u32x4{pack2(da.x, da.y), pack2(da.z, da.w), pack2(db.x, db.y), pack2(db.z, db.w)};
    *(u32x4*)(myrow + 10 * 16) =
        u32x4{pack2(dc4.x, dc4.y), pack2(dc4.z, dc4.w), pack2(dd4.x, dd4.y), pack2(dd4.z, dd4.w)};
    *(u32x4*)(myrow + 11 * 16) = u32x4{0u, 0u, 0u, 0u};
  }

  const float v1f[12] = {va.x, va.y, va.z, va.w, vb.x, vb.y, vb.z, vb.w,
                         vc.x, vc.y, vc.z, vc.w};

  // ---- hoist ef fragments (B-operand: lane holds ef[e=g*16+lc][k=(ks*4+lq)*8+j]) ----
  half8 eff[4][3];
#pragma unroll
  for (int g = 0; g < 4; ++g) {
    const char* rp = ub + (wv * 64 + g * 16 + lc) * kRowB;
#pragma unroll
    for (int ks = 0; ks < 3; ++ks)
      eff[g][ks] = *(const half8*)(rp + (ks * 4 + lq) * 16);
  }

  // ---- stash sh/v1 as f32 into chunks 8..11 (ef chunks 8..11 now dead) ----
  *(f32x4*)(myrow + 8 * 16) = f32x4{sh0, sh1, sh2, v1f[0]};
  *(f32x4*)(myrow + 9 * 16) = f32x4{v1f[1], v1f[2], v1f[3], v1f[4]};
  *(f32x4*)(myrow + 10 * 16) = f32x4{v1f[5], v1f[6], v1f[7], v1f[8]};
  *(f32x4*)(myrow + 11 * 16) = f32x4{v1f[9], v1f[10], v1f[11], 0.0f};

  // ---- MFMA-1: h[n][e] = relu(b1[n] + sum_k W1p[k][n] ef[e][k]) ----
#pragma unroll
  for (int nt = 0; nt < 4; ++nt) {
    const half8 a0 = *(const half8*)(img1 + ((0 + lq) * 64 + nt * 16 + lc) * 16);
    const half8 a1 = *(const half8*)(img1 + ((4 + lq) * 64 + nt * 16 + lc) * 16);
    const half8 a2 = *(const half8*)(img1 + ((8 + lq) * 64 + nt * 16 + lc) * 16);
    const f32x4 bias = *(const f32x4*)(b1 + nt * 16 + lq * 4);
#pragma unroll
    for (int g = 0; g < 4; ++g) {
      f32x4 acc = bias;
      acc = __builtin_amdgcn_mfma_f32_16x16x32_f16(a0, eff[g][0], acc, 0, 0, 0);
      acc = __builtin_amdgcn_mfma_f32_16x16x32_f16(a1, eff[g][1], acc, 0, 0, 0);
      acc = __builtin_amdgcn_mfma_f32_16x16x32_f16(a2, eff[g][2], acc, 0, 0, 0);
      const unsigned p0 = pack2(fmaxf(acc[0], 0.0f), fmaxf(acc[1], 0.0f));
      const unsigned p1 = pack2(fmaxf(acc[2], 0.0f), fmaxf(acc[3], 0.0f));
      const int row = wv * 64 + g * 16 + lc;
      // n = nt*16 + lq*4 + r -> byte 2n = nt*32 + lq*8
      *(u32x2*)(ub + row * kRowB + nt * 32 + lq * 8) = u32x2{p0, p1};
    }
  }

  // ---- load h fragments (B-operand: lane holds h[k][e=g*16+lc]) ----
  half8 hf[4][2];
#pragma unroll
  for (int g = 0; g < 4; ++g) {
    const char* rp = ub + (wv * 64 + g * 16 + lc) * kRowB;
    hf[g][0] = *(const half8*)(rp + (0 + lq) * 16);
    hf[g][1] = *(const half8*)(rp + (4 + lq) * 16);
  }

  // ---- hoist per-edge sh / v1 (lane owns edge lc of each group) ----
  float shv[4][3], v1h[4][3];
#pragma unroll
  for (int g = 0; g < 4; ++g) {
    const char* rp = ub + (wv * 64 + g * 16 + lc) * kRowB;
#pragma unroll
    for (int c = 0; c < 3; ++c) {
      shv[g][c] = *(const float*)(rp + 128 + 4 * c);
      v1h[g][c] = *(const float*)(rp + 140 + 12 * lq + 4 * c);
    }
  }

  // ---- o0[20] as f32 into chunks 0..4 (h region dead now that hf is in regs) ----
  {
    const float t0 = (v1f[0] * sh0 + v1f[1] * sh1 + v1f[2] * sh2) * kInvSqrt3;
    const float t1 = (v1f[3] * sh0 + v1f[4] * sh1 + v1f[5] * sh2) * kInvSqrt3;
    const float t2 = (v1f[6] * sh0 + v1f[7] * sh1 + v1f[8] * sh2) * kInvSqrt3;
    const float t3 = (v1f[9] * sh0 + v1f[10] * sh1 + v1f[11] * sh2) * kInvSqrt3;
    *(f32x4*)(myrow + 0) = f32x4{sa.x, sa.y, sa.z, sa.w};
    *(f32x4*)(myrow + 16) = f32x4{sb.x, sb.y, sb.z, sb.w};
    *(f32x4*)(myrow + 32) = f32x4{sc4.x, sc4.y, sc4.z, sc4.w};
    *(f32x4*)(myrow + 48) = f32x4{sd4.x, sd4.y, sd4.z, sd4.w};
    *(f32x4*)(myrow + 64) = f32x4{t0, t1, t2, t3};
  }

  // ---- MFMA-2 + fused contraction. D[n][e]: lane owns edge lc, n = 16nt+4lq+r ----
  float macc0[4][4] = {};
  float macc1[4][4][3] = {};

#pragma unroll 5
  for (int nt = 0; nt < 20; ++nt) {
    const half8 w0 = *(const half8*)(img2 + ((0 + lq) * 400 + nt * 16 + lc) * 16);
    const half8 w1 = *(const half8*)(img2 + ((4 + lq) * 400 + nt * 16 + lc) * 16);
    const f32x4 bias = *(const f32x4*)(b2 + nt * 16 + lq * 4);
#pragma unroll
    for (int g = 0; g < 4; ++g) {
      f32x4 acc = bias;
      acc = __builtin_amdgcn_mfma_f32_16x16x32_f16(w0, hf[g][0], acc, 0, 0, 0);
      acc = __builtin_amdgcn_mfma_f32_16x16x32_f16(w1, hf[g][1], acc, 0, 0, 0);
      const char* rp0 = ub + (wv * 64 + g * 16 + lc) * kRowB;
      const float o0v = *(const float*)(rp0 + 4 * nt);   // broadcast (4 lanes/addr)
#pragma unroll
      for (int r = 0; r < 4; ++r) macc0[g][r] = fmaf(o0v, acc[r], macc0[g][r]);
    }
  }
#pragma unroll
  for (int nt = 20; nt < 24; ++nt) {
    const half8 w0 = *(const half8*)(img2 + ((0 + lq) * 400 + nt * 16 + lc) * 16);
    const half8 w1 = *(const half8*)(img2 + ((4 + lq) * 400 + nt * 16 + lc) * 16);
    const f32x4 bias = *(const f32x4*)(b2 + nt * 16 + lq * 4);
#pragma unroll
    for (int g = 0; g < 4; ++g) {
      f32x4 acc = bias;
      acc = __builtin_amdgcn_mfma_f32_16x16x32_f16(w0, hf[g][0], acc, 0, 0, 0);
      acc = __builtin_amdgcn_mfma_f32_16x16x32_f16(w1, hf[g][1], acc, 0, 0, 0);
      const char* rp0 = ub + (wv * 64 + g * 16 + lc) * kRowB;
      // i = 4*(nt-20) + lq, o = r; o1[i] = ss[i] * sh; ss[i] = o0[i] (f32)
      const float ssv = *(const float*)(rp0 + 16 * (nt - 20) + 4 * lq);
      float pc[3];
#pragma unroll
      for (int c = 0; c < 3; ++c) pc[c] = ssv * shv[g][c];
#pragma unroll
      for (int r = 0; r < 4; ++r)
#pragma unroll
        for (int c = 0; c < 3; ++c)
          macc1[g][r][c] = fmaf(pc[c], acc[r], macc1[g][r][c]);
    }
  }
  {  // nt = 24: i = 16 + lq, o1 row = in_1o
    const int nt = 24;
    const half8 w0 = *(const half8*)(img2 + ((0 + lq) * 400 + nt * 16 + lc) * 16);
    const half8 w1 = *(const half8*)(img2 + ((4 + lq) * 400 + nt * 16 + lc) * 16);
    const f32x4 bias = *(const f32x4*)(b2 + nt * 16 + lq * 4);
#pragma unroll
    for (int g = 0; g < 4; ++g) {
      f32x4 acc = bias;
      acc = __builtin_amdgcn_mfma_f32_16x16x32_f16(w0, hf[g][0], acc, 0, 0, 0);
      acc = __builtin_amdgcn_mfma_f32_16x16x32_f16(w1, hf[g][1], acc, 0, 0, 0);
#pragma unroll
      for (int r = 0; r < 4; ++r)
#pragma unroll
        for (int c = 0; c < 3; ++c)
          macc1[g][r][c] = fmaf(v1h[g][c], acc[r], macc1[g][r][c]);
    }
  }

  // ---- finish msg1 (reduce i-partition across lq groups), scale, write msg rows ----
#pragma unroll
  for (int g = 0; g < 4; ++g)
#pragma unroll
    for (int r = 0; r < 4; ++r)
#pragma unroll
      for (int c = 0; c < 3; ++c) {
        float x = macc1[g][r][c];
        x += __shfl_xor(x, 16);
        x += __shfl_xor(x, 32);
        macc1[g][r][c] = x * kInvSqrt20;
      }
#pragma unroll
  for (int g = 0; g < 4; ++g) {
    char* rp = ub + (wv * 64 + g * 16 + lc) * kRowB;
    *(f32x4*)(rp + lq * 16) =
        f32x4{macc0[g][0] * kInvSqrt20, macc0[g][1] * kInvSqrt20,
              macc0[g][2] * kInvSqrt20, macc0[g][3] * kInvSqrt20};
    f32x4 m1;
    if (lq == 1)
      m1 = f32x4{macc1[g][0][0], macc1[g][0][1], macc1[g][0][2], macc1[g][1][0]};
    else if (lq == 2)
      m1 = f32x4{macc1[g][1][1], macc1[g][1][2], macc1[g][2][0], macc1[g][2][1]};
    else
      m1 = f32x4{macc1[g][2][2], macc1[g][3][0], macc1[g][3][1], macc1[g][3][2]};
    if (lq != 0) *(f32x4*)(rp + 48 + lq * 16) = m1;
  }

  // ---- read back own msg, segmented wave reduction, one atomic per segment head ----
  float msg[28];
  {
    const char* rp = ub + tid * kRowB;
#pragma unroll
    for (int c = 0; c < 7; ++c) {
      const f32x4 v = *(const f32x4*)(rp + c * 16);
      msg[c * 4 + 0] = v[0];
      msg[c * 4 + 1] = v[1];
      msg[c * 4 + 2] = v[2];
      msg[c * 4 + 3] = v[3];
    }
  }
#pragma unroll
  for (int d = 1; d < 64; d <<= 1) {
    const int od = __shfl_down(dstv, d);
    const bool same = (lane + d < 64) && (od == dstv);
#pragma unroll
    for (int j = 0; j < 28; j++) {
      const float ov = __shfl_down(msg[j], d);
      if (same) msg[j] += ov;
    }
  }
  const int pd = __shfl_up(dstv, 1);
  if ((lane == 0 || pd != dstv) && dstv >= 0) {
    // pre-normalize: agg was seeded with node_attr; adding msg/cnt completes
    // out = node_attr + (segment-sum)/cnt without a finalize pass.
    const float rc = 1.0f / fmaxf((float)cnt[dstv], 1.0f);
    float* ap = agg + (size_t)dstv * kAttr;
#pragma unroll
    for (int j = 0; j < 28; j++) atomicAdd(ap + j, msg[j] * rc);
  }
}

extern "C" void kernel_launch(void* const* d_in, const int* in_sizes, int n_in,
                              void* d_out, int out_size, void* d_ws, size_t ws_size,
                              hipStream_t stream) {
  const float* node_attr = (const float*)d_in[0];
  const float* pos = (const float*)d_in[1];
  const float* W1 = (const float*)d_in[2];
  const float* b1 = (const float*)d_in[3];
  const float* W2 = (const float*)d_in[4];
  const float* b2 = (const float*)d_in[5];
  const int* edge_index = (const int*)d_in[6];

  const int N = in_sizes[0] / kAttr;
  const int E = in_sizes[6] / 2;

  // ws layout: [img1][img2][cnt N][node_start N][rank E][sedge E int2] ~4.0MB
  char* wsc = (char*)d_ws;
  unsigned short* img1 = (unsigned short*)wsc;
  unsigned short* img2 = (unsigned short*)(wsc + kImg1Bytes);
  int* cnt = (int*)(wsc + kImg1Bytes + kImg2Bytes);
  int* node_start = cnt + N;
  int* rank = node_start + N;
  int2* sedge = (int2*)(rank + E);

  float* agg = (float*)d_out;
  const int aggN4 = out_size / 4;
  const int eblocks = (E + 255) / 256;

  // 5 dispatches, all plain (r9: no grid.sync; r8: no mega-fuse; r12: no
  // finalize). r13: one atomic pass only; scatter is rank-addressed.
  init_kernel<<<512, 256, 0, stream>>>(W1, W2, node_attr, img1, img2, cnt, agg,
                                       aggN4, N);
  hist_rank_kernel<<<eblocks, 256, 0, stream>>>(edge_index, cnt, rank, E);
  scan_kernel<<<1, 256, 0, stream>>>(cnt, node_start, N);
  scatter_kernel<<<eblocks, 256, 0, stream>>>(edge_index, node_start, rank,
                                              sedge, E);
  tfn_mfma_kernel<<<eblocks, 256, 0, stream>>>(
      node_attr, pos, b1, b2, (const char*)img1, (const char*)img2,
      sedge, cnt, agg, E);
}